// Round 9
// baseline (2876.430 us; speedup 1.0000x reference)
//
#include <hip/hip_runtime.h>

#define BB 4
#define NN 8192
#define SS 2048
#define KK 16

typedef float v2f __attribute__((ext_vector_type(2)));

// R19: spatially-pruned exact KNN. R8 post-mortem: fps at structural floor (1555us); tail knn ~300us is
// the largest item, cost = insertion chain firing every brute-force step. This round: Morton-sorted
// candidates (+orig idx) & slice AABBs built by idle worker blocks under fps's shadow; fps Morton-sorts
// its 2048 samples in a ~10us epilogue (queries spatially compact per wave). New knn: 1 wave = 64 sorted
// queries, zigzag slice walk, per-lane AABB skip-check with margin (false-skip impossible; theta only
// shrinks so skip-at-check-time is final-valid), __all -> skip slice. d2 arithmetic + insertion chain
// VERBATIM from the verified kernel. No merge phase. Self-KNN reuses sorted queries as candidates.
__device__ __forceinline__ float wred_max(float v) {
  float s;
  s = __int_as_float(__builtin_amdgcn_update_dpp(0, __float_as_int(v), 0x111, 0xf, 0xf, true)); v = fmaxf(v, s);
  s = __int_as_float(__builtin_amdgcn_update_dpp(0, __float_as_int(v), 0x112, 0xf, 0xf, true)); v = fmaxf(v, s);
  s = __int_as_float(__builtin_amdgcn_update_dpp(0, __float_as_int(v), 0x114, 0xf, 0xf, true)); v = fmaxf(v, s);
  s = __int_as_float(__builtin_amdgcn_update_dpp(0, __float_as_int(v), 0x118, 0xf, 0xf, true)); v = fmaxf(v, s);
  s = __int_as_float(__builtin_amdgcn_update_dpp(0, __float_as_int(v), 0x142, 0xf, 0xf, true)); v = fmaxf(v, s);
  s = __int_as_float(__builtin_amdgcn_update_dpp(0, __float_as_int(v), 0x143, 0xf, 0xf, true)); v = fmaxf(v, s);
  return v;   // lane63 = wave max; 0-fill only widens boxes (safe for AABB use)
}
__device__ __forceinline__ float wred_min(float v) {
  float s;
  s = __int_as_float(__builtin_amdgcn_update_dpp(0, __float_as_int(v), 0x111, 0xf, 0xf, true)); v = fminf(v, s);
  s = __int_as_float(__builtin_amdgcn_update_dpp(0, __float_as_int(v), 0x112, 0xf, 0xf, true)); v = fminf(v, s);
  s = __int_as_float(__builtin_amdgcn_update_dpp(0, __float_as_int(v), 0x114, 0xf, 0xf, true)); v = fminf(v, s);
  s = __int_as_float(__builtin_amdgcn_update_dpp(0, __float_as_int(v), 0x118, 0xf, 0xf, true)); v = fminf(v, s);
  s = __int_as_float(__builtin_amdgcn_update_dpp(0, __float_as_int(v), 0x142, 0xf, 0xf, true)); v = fminf(v, s);
  s = __int_as_float(__builtin_amdgcn_update_dpp(0, __float_as_int(v), 0x143, 0xf, 0xf, true)); v = fminf(v, s);
  return v;
}
__device__ __forceinline__ int morton8(float x, float y, float z,
                                       float mnx, float mny, float mnz,
                                       float scx, float scy, float scz) {
  int qx = min(7, (int)((x - mnx) * scx));
  int qy = min(7, (int)((y - mny) * scy));
  int qz = min(7, (int)((z - mnz) * scz));
  return (qx&1) | ((qy&1)<<1) | ((qz&1)<<2)
       | ((qx&2)<<2) | ((qy&2)<<3) | ((qz&2)<<4)
       | ((qx&4)<<4) | ((qy&4)<<5) | ((qz&4)<<6);
}

#define FTH 512
#define FPT (NN/FTH)  // 16 points per thread
#define TRB 256       // transpose blocks
#define SPB 124       // spinner blocks
__global__ __launch_bounds__(FTH, 1) void fps_kernel(
    const float* __restrict__ xyz,    // [B,3,N]
    const float* __restrict__ points, // [B,64,N]
    float* __restrict__ out_newxyz,   // [B,3,S]
    float* __restrict__ ptst,         // [B,N,64]
    float4* __restrict__ csorted,     // [B][8192] sorted candidates (x,y,z,origidx)
    float*  __restrict__ caabb,       // [B][32][8] slice AABBs
    float4* __restrict__ qsorted,     // [B][2048] sorted queries (x,y,z,orig_s)
    float*  __restrict__ qaabb,       // [B][8][8]
    int* __restrict__ spin_flag)
{
  #pragma clang fp contract(off)
  const int blk = blockIdx.x;
  const int tid = threadIdx.x;
  const int wave = tid >> 6;
  const int lane = tid & 63;
  __shared__ __align__(16) float4 sxyz[NN];                // 128 KB sorted points
  __shared__ __align__(16) unsigned long long skey[2][8];  // per-wave packed (maxdist,~idx), dbuf
  __shared__ int smi[SS];                                  // scan scratch / winner history
  __shared__ float sred[8*6];                              // per-wave bbox partials
  __shared__ float tile[32][33];                           // transpose-role tile

  if (blk >= BB) {
    if (blk < BB + TRB) {
      // ---------- transpose role: points [B,64,N] -> ptst [B,N,64], 8 tiles of 32x32 ----------
      if (blk == BB && tid == 0) spin_flag[8] = 0;         // zero bn-fusion counter
      const int x = tid & 31, yy = tid >> 5;               // 32 x 16
      for (int q = 0; q < 8; ++q) {
        const int tj = (blk - BB)*8 + q;                   // [0, 2048)
        const int tn = tj & 255, tc = (tj >> 8) & 1, tb = tj >> 9;
        const int n0 = tn*32, c0 = tc*32;
        __syncthreads();
        tile[yy][x]    = points[(tb*64 + c0+yy)*NN + n0+x];
        tile[yy+16][x] = points[(tb*64 + c0+yy+16)*NN + n0+x];
        __syncthreads();
        ptst[(tb*NN + n0+yy)*64 + c0+x]    = tile[x][yy];
        ptst[(tb*NN + n0+yy+16)*64 + c0+x] = tile[x][yy+16];
      }
      if (blk - BB < BB) {
        // ---------- candidate-structure builder (hidden under fps's ~1.5ms): batch b2 ----------
        const int b2 = blk - BB;
        const float* xb2 = xyz + b2*3*NN;
        float tx[FPT], ty[FPT], tz[FPT];
        #pragma unroll
        for (int j = 0; j < FPT; ++j) {
          int i = tid + j*FTH;
          tx[j] = xb2[i]; ty[j] = xb2[NN+i]; tz[j] = xb2[2*NN+i];
        }
        float mnx = tx[0], mxx = tx[0], mny = ty[0], mxy = ty[0], mnz = tz[0], mxz = tz[0];
        #pragma unroll
        for (int j = 1; j < FPT; ++j) {
          mnx = fminf(mnx, tx[j]); mxx = fmaxf(mxx, tx[j]);
          mny = fminf(mny, ty[j]); mxy = fmaxf(mxy, ty[j]);
          mnz = fminf(mnz, tz[j]); mxz = fmaxf(mxz, tz[j]);
        }
        mnx = wred_min(mnx); mxx = wred_max(mxx);
        mny = wred_min(mny); mxy = wred_max(mxy);
        mnz = wred_min(mnz); mxz = wred_max(mxz);
        if (lane == 63) {
          sred[wave*6+0] = mnx; sred[wave*6+1] = mxx; sred[wave*6+2] = mny;
          sred[wave*6+3] = mxy; sred[wave*6+4] = mnz; sred[wave*6+5] = mxz;
        }
        smi[tid] = 0;
        __syncthreads();
        #pragma unroll
        for (int w = 0; w < 8; ++w) {
          mnx = fminf(mnx, sred[w*6+0]); mxx = fmaxf(mxx, sred[w*6+1]);
          mny = fminf(mny, sred[w*6+2]); mxy = fmaxf(mxy, sred[w*6+3]);
          mnz = fminf(mnz, sred[w*6+4]); mxz = fmaxf(mxz, sred[w*6+5]);
        }
        const float scx = 8.0f / (mxx - mnx + 1e-12f);
        const float scy = 8.0f / (mxy - mny + 1e-12f);
        const float scz = 8.0f / (mxz - mnz + 1e-12f);
        int cells[FPT];
        #pragma unroll
        for (int j = 0; j < FPT; ++j) {
          cells[j] = morton8(tx[j], ty[j], tz[j], mnx, mny, mnz, scx, scy, scz);
          atomicAdd(&smi[cells[j]], 1);
        }
        __syncthreads();
        for (int d = 1; d < 512; d <<= 1) {
          int v = smi[tid];
          int a = (tid >= d) ? smi[tid - d] : 0;
          __syncthreads();
          smi[tid] = v + a;
          __syncthreads();
        }
        { int excl = (tid == 0) ? 0 : smi[tid - 1]; smi[512 + tid] = excl; }
        __syncthreads();
        #pragma unroll
        for (int j = 0; j < FPT; ++j) {
          int pos = atomicAdd(&smi[512 + cells[j]], 1);
          csorted[b2*NN + pos] = make_float4(tx[j], ty[j], tz[j], __int_as_float(tid + j*FTH));
        }
        __syncthreads();   // drain scatter (same-CU L2 reads below are then coherent)
        // slice AABBs: wave w handles slices w, w+8, w+16, w+24 (256 pts each; 4/lane)
        for (int sl = wave; sl < 32; sl += 8) {
          float a0x=1e30f, a1x=-1e30f, a0y=1e30f, a1y=-1e30f, a0z=1e30f, a1z=-1e30f;
          #pragma unroll
          for (int t = 0; t < 4; ++t) {
            float4 c = csorted[b2*NN + sl*256 + lane*4 + t];
            a0x = fminf(a0x, c.x); a1x = fmaxf(a1x, c.x);
            a0y = fminf(a0y, c.y); a1y = fmaxf(a1y, c.y);
            a0z = fminf(a0z, c.z); a1z = fmaxf(a1z, c.z);
          }
          a0x = wred_min(a0x); a1x = wred_max(a1x);
          a0y = wred_min(a0y); a1y = wred_max(a1y);
          a0z = wred_min(a0z); a1z = wred_max(a1z);
          if (lane == 63) {
            float* o = caabb + (b2*32 + sl)*8;
            o[0]=a0x; o[1]=a1x; o[2]=a0y; o[3]=a1y; o[4]=a0z; o[5]=a1z;
          }
        }
      }
      return;
    }
    // ---------- spinner role: wave 0 only; FMA activity; exit on fps done ----------
    if (tid >= 64) return;
    const int s0 = atomicAdd(spin_flag, 0);
    float a0 = 1.0f + tid, a1 = 2.0f, a2 = 3.0f, a3 = 4.0f;
    for (int outer = 0; outer < 50000; ++outer) {
      #pragma unroll
      for (int u = 0; u < 256; ++u) {
        a0 = fmaf(a0, 1.0000001f, 1e-7f);
        a1 = fmaf(a1, 0.9999999f, 2e-7f);
        a2 = fmaf(a2, 1.0000002f, 3e-7f);
        a3 = fmaf(a3, 0.9999998f, 4e-7f);
      }
      if (atomicAdd(spin_flag, 0) - s0 >= BB) break;
    }
    asm volatile("" :: "v"(a0), "v"(a1), "v"(a2), "v"(a3));
    return;
  }

  // ---------------- fps role: EXACT R13/R18 structure ----------------
  const int b = blk;
  const float* xb = xyz + b*3*NN;

  float tx[FPT], ty[FPT], tz[FPT];
  #pragma unroll
  for (int j = 0; j < FPT; ++j) {
    int i = tid + j*FTH;
    tx[j] = xb[i]; ty[j] = xb[NN+i]; tz[j] = xb[2*NN+i];
  }
  float mnx = tx[0], mxx = tx[0], mny = ty[0], mxy = ty[0], mnz = tz[0], mxz = tz[0];
  #pragma unroll
  for (int j = 1; j < FPT; ++j) {
    mnx = fminf(mnx, tx[j]); mxx = fmaxf(mxx, tx[j]);
    mny = fminf(mny, ty[j]); mxy = fmaxf(mxy, ty[j]);
    mnz = fminf(mnz, tz[j]); mxz = fmaxf(mxz, tz[j]);
  }
  mnx = wred_min(mnx); mxx = wred_max(mxx);
  mny = wred_min(mny); mxy = wred_max(mxy);
  mnz = wred_min(mnz); mxz = wred_max(mxz);
  if (lane == 63) {
    sred[wave*6+0] = mnx; sred[wave*6+1] = mxx; sred[wave*6+2] = mny;
    sred[wave*6+3] = mxy; sred[wave*6+4] = mnz; sred[wave*6+5] = mxz;
  }
  smi[tid] = 0;                       // zero hist region [0,512)
  __syncthreads();
  #pragma unroll
  for (int w = 0; w < 8; ++w) {
    mnx = fminf(mnx, sred[w*6+0]); mxx = fmaxf(mxx, sred[w*6+1]);
    mny = fminf(mny, sred[w*6+2]); mxy = fmaxf(mxy, sred[w*6+3]);
    mnz = fminf(mnz, sred[w*6+4]); mxz = fmaxf(mxz, sred[w*6+5]);
  }
  const float scx = 8.0f / (mxx - mnx + 1e-12f);
  const float scy = 8.0f / (mxy - mny + 1e-12f);
  const float scz = 8.0f / (mxz - mnz + 1e-12f);
  int cells[FPT];
  #pragma unroll
  for (int j = 0; j < FPT; ++j) {
    cells[j] = morton8(tx[j], ty[j], tz[j], mnx, mny, mnz, scx, scy, scz);
    atomicAdd(&smi[cells[j]], 1);
  }
  __syncthreads();
  for (int d = 1; d < 512; d <<= 1) {
    int v = smi[tid];
    int a = (tid >= d) ? smi[tid - d] : 0;
    __syncthreads();
    smi[tid] = v + a;
    __syncthreads();
  }
  {
    int excl = (tid == 0) ? 0 : smi[tid - 1];
    smi[512 + tid] = excl;
  }
  __syncthreads();
  #pragma unroll
  for (int j = 0; j < FPT; ++j) {
    int pos = atomicAdd(&smi[512 + cells[j]], 1);
    sxyz[pos] = make_float4(tx[j], ty[j], tz[j], 0.0f);
  }
  __syncthreads();
  v2f px[FPT/2], py[FPT/2], pz[FPT/2], dist[FPT/2];
  float bx0, bx1, by0, by1, bz0, bz1;
  {
    float4 c0 = sxyz[tid*FPT];
    bx0 = bx1 = c0.x; by0 = by1 = c0.y; bz0 = bz1 = c0.z;
    #pragma unroll
    for (int e = 0; e < FPT; ++e) {
      float4 cc = sxyz[tid*FPT + e];
      ((float*)px)[e] = cc.x; ((float*)py)[e] = cc.y; ((float*)pz)[e] = cc.z;
      ((float*)dist)[e] = 1e10f;
      bx0 = fminf(bx0, cc.x); bx1 = fmaxf(bx1, cc.x);
      by0 = fminf(by0, cc.y); by1 = fmaxf(by1, cc.y);
      bz0 = fminf(bz0, cc.z); bz1 = fmaxf(bz1, cc.z);
    }
  }
  float dmax = 1e10f;
  int   beste = 0;
  float cx = xb[0], cy = xb[NN], cz = xb[2*NN];   // iteration-0 centroid = ORIGINAL point 0
  __syncthreads();
  for (int it = 1; it < SS; ++it) {
    const int buf = it & 1;
    float gx = fmaxf(fmaxf(bx0 - cx, cx - bx1), 0.0f);
    float gy = fmaxf(fmaxf(by0 - cy, cy - by1), 0.0f);
    float gz = fmaxf(fmaxf(bz0 - cz, cz - bz1), 0.0f);
    float lb = gx*gx + gy*gy; lb = lb + gz*gz;
    if (lb * 0.99999f < dmax) {
      v2f cx2 = {cx, cx}, cy2 = {cy, cy}, cz2 = {cz, cz};
      v2f vmax = {-1.0f, -1.0f};
      #pragma unroll
      for (int j = 0; j < FPT/2; ++j) {
        v2f dx = px[j] - cx2, dy = py[j] - cy2, dz = pz[j] - cz2;
        v2f d = dx*dx + dy*dy;
        d = d + dz*dz;
        v2f nd = __builtin_elementwise_min(dist[j], d);
        dist[j] = nd;
        vmax = __builtin_elementwise_max(vmax, nd);
      }
      float mloc = fmaxf(vmax.x, vmax.y);
      int ce[FPT/2];
      #pragma unroll
      for (int j = 0; j < FPT/2; ++j) {
        int c = 0x7FFFFFFF;
        if (dist[j].y == mloc) c = 2*j + 1;
        if (dist[j].x == mloc) c = 2*j;
        ce[j] = c;
      }
      #pragma unroll
      for (int st = FPT/4; st >= 1; st >>= 1) {
        #pragma unroll
        for (int j = 0; j < st; ++j) ce[j] = ce[j] < ce[j+st] ? ce[j] : ce[j+st];
      }
      dmax = mloc;
      beste = ce[0];
    }
    // R18 wave argmax: f32 max ladder + ballot + readlane (verified)
    float wm = dmax;
    wm = wred_max(wm);
    wm = __int_as_float(__builtin_amdgcn_readlane(__float_as_int(wm), 63));
    unsigned long long em = __ballot(dmax == wm);
    int lw = (int)__ffsll((unsigned long long)em) - 1;
    int bi_w = __builtin_amdgcn_readlane((tid << 4) + beste, lw);
    if (lane == 63) skey[buf][wave] = ((unsigned long long)__float_as_uint(wm) << 32) | (unsigned)~bi_w;
    __syncthreads();
    const ulonglong2* kp = (const ulonglong2*)&skey[buf][0];
    ulonglong2 k01 = kp[0], k23 = kp[1], k45 = kp[2], k67 = kp[3];
    unsigned long long m0 = k01.x > k01.y ? k01.x : k01.y;
    unsigned long long m1 = k23.x > k23.y ? k23.x : k23.y;
    unsigned long long m2 = k45.x > k45.y ? k45.x : k45.y;
    unsigned long long m3 = k67.x > k67.y ? k67.x : k67.y;
    unsigned long long ma = m0 > m1 ? m0 : m1;
    unsigned long long mb = m2 > m3 ? m2 : m3;
    unsigned long long mk = ma > mb ? ma : mb;
    int mi = (int)(~(unsigned)mk);
    float4 c = sxyz[mi];
    if (tid == 0) smi[it] = mi;
    cx = c.x; cy = c.y; cz = c.z;
  }
  __syncthreads();
  // epilogue: write sampled coords; it=0 from ORIGINAL point 0
  for (int it = tid; it < SS; it += FTH) {
    float x, y, z;
    if (it == 0) { x = xb[0]; y = xb[NN]; z = xb[2*NN]; }
    else { float4 c = sxyz[smi[it]]; x = c.x; y = c.y; z = c.z; }
    out_newxyz[(b*3+0)*SS + it] = x;
    out_newxyz[(b*3+1)*SS + it] = y;
    out_newxyz[(b*3+2)*SS + it] = z;
  }
  // ---- R19: Morton-sort the 2048 samples -> qsorted (+orig s), 8 slice AABBs -> qaabb ----
  float4 qp4[4]; int qj4[4], qc4[4];
  #pragma unroll
  for (int k2 = 0; k2 < 4; ++k2) {
    int j = tid + k2*FTH;
    float4 p;
    if (j == 0) p = make_float4(xb[0], xb[NN], xb[2*NN], 0.0f);
    else        p = sxyz[smi[j]];
    qp4[k2] = p; qj4[k2] = j;
  }
  __syncthreads();            // done reading smi history
  smi[tid] = 0;
  __syncthreads();
  #pragma unroll
  for (int k2 = 0; k2 < 4; ++k2) {
    qc4[k2] = morton8(qp4[k2].x, qp4[k2].y, qp4[k2].z, mnx, mny, mnz, scx, scy, scz);
    atomicAdd(&smi[qc4[k2]], 1);
  }
  __syncthreads();
  for (int d = 1; d < 512; d <<= 1) {
    int v = smi[tid];
    int a = (tid >= d) ? smi[tid - d] : 0;
    __syncthreads();
    smi[tid] = v + a;
    __syncthreads();
  }
  { int excl = (tid == 0) ? 0 : smi[tid - 1]; smi[512 + tid] = excl; }
  __syncthreads();
  #pragma unroll
  for (int k2 = 0; k2 < 4; ++k2) {
    int pos = atomicAdd(&smi[512 + qc4[k2]], 1);
    qsorted[b*SS + pos] = make_float4(qp4[k2].x, qp4[k2].y, qp4[k2].z, __int_as_float(qj4[k2]));
  }
  __syncthreads();            // drain scatter; same-CU reads below coherent
  {
    float a0x=1e30f, a1x=-1e30f, a0y=1e30f, a1y=-1e30f, a0z=1e30f, a1z=-1e30f;
    #pragma unroll
    for (int t = 0; t < 4; ++t) {
      float4 c = qsorted[b*SS + wave*256 + lane*4 + t];
      a0x = fminf(a0x, c.x); a1x = fmaxf(a1x, c.x);
      a0y = fminf(a0y, c.y); a1y = fmaxf(a1y, c.y);
      a0z = fminf(a0z, c.z); a1z = fmaxf(a1z, c.z);
    }
    a0x = wred_min(a0x); a1x = wred_max(a1x);
    a0y = wred_min(a0y); a1y = wred_max(a1y);
    a0z = wred_min(a0z); a1z = wred_max(a1z);
    if (lane == 63) {
      float* o = qaabb + (b*8 + wave)*8;
      o[0]=a0x; o[1]=a1x; o[2]=a0y; o[3]=a1y; o[4]=a0z; o[5]=a1z;
    }
  }
  if (tid == 0) atomicAdd(spin_flag, 1);   // release spinners
}

// ---------------- KNN: 1 wave = 64 Morton-adjacent queries, AABB-pruned slice walk ----------------
__global__ __launch_bounds__(64) void knn_kernel(
    const float4* __restrict__ qsorted, // [B][2048]
    const float*  __restrict__ qaabb,   // [B][8][8]
    const float4* __restrict__ csorted, // [B][8192]
    const float*  __restrict__ caabb,   // [B][32][8]
    int* __restrict__ out1,             // [B,S,K] vs xyz (orig indices)
    int* __restrict__ out2)             // [B,S,K] self (s indices)
{
  #pragma clang fp contract(off)
  __shared__ float4 sc[256];
  __shared__ int    sidx[256];
  const int bid = blockIdx.x;
  const int half = bid >> 7;
  const int rem = bid & 127;
  const int b = rem >> 5;
  const int wslot = rem & 31;
  const int lane = threadIdx.x;
  const float4* cand = half ? (qsorted + b*SS) : (csorted + b*NN);
  const float*  aabb = half ? (qaabb + b*8*8) : (caabb + b*32*8);
  const int nsl = half ? 8 : 32;
  const int s0 = half ? (wslot >> 2) : wslot;
  int* outidx = half ? out2 : out1;

  float4 q = qsorted[b*SS + wslot*64 + lane];
  const int orig_s = __float_as_int(q.w);
  const float qx = q.x, qy = q.y, qz = q.z;
  float sq = qx*qx + qy*qy; sq = sq + qz*qz;
  float d16[16]; int i16[16];
  #pragma unroll
  for (int j = 0; j < 16; ++j) { d16[j] = 1e30f; i16[j] = 0x7FFFFFFF; }

  for (int j = 0; j < nsl; ++j) {
    int off = (j + 1) >> 1;
    int s = (s0 + ((j & 1) ? off : -off)) & (nsl - 1);   // zigzag from home slice, distinct mod nsl
    const float* ab = aabb + s*8;
    // per-lane exact skip: margin 1e-3 abs >> formula cancellation (~4e-5) -> false-skip impossible.
    // theta only shrinks -> skip valid at check time is valid finally.
    float gx = fmaxf(fmaxf(ab[0] - qx, qx - ab[1]), 0.0f);
    float gy = fmaxf(fmaxf(ab[2] - qy, qy - ab[3]), 0.0f);
    float gz = fmaxf(fmaxf(ab[4] - qz, qz - ab[5]), 0.0f);
    float lbnd = gx*gx + gy*gy; lbnd = lbnd + gz*gz;
    bool skip = (lbnd * 0.9999f - 1e-3f) > d16[15];
    if (__all(skip)) continue;
    #pragma unroll
    for (int t = 0; t < 4; ++t) {
      float4 c = cand[s*256 + t*64 + lane];
      float pp = c.x*c.x + c.y*c.y; pp = pp + c.z*c.z;
      sidx[t*64 + lane] = __float_as_int(c.w);
      sc[t*64 + lane] = make_float4(c.x, c.y, c.z, pp);
    }
    __syncthreads();
    for (int t = 0; t < 256; ++t) {
      float4 c = sc[t];
      float qp = qx*c.x + qy*c.y; qp = qp + qz*c.z;
      float d2 = (sq + c.w) - 2.0f*qp;
      if (d2 < d16[15]) {
        d16[15] = d2; i16[15] = sidx[t];
        #pragma unroll
        for (int u = 15; u > 0; --u) {
          if (d16[u] < d16[u-1]) {
            float td = d16[u]; d16[u] = d16[u-1]; d16[u-1] = td;
            int   ti = i16[u]; i16[u] = i16[u-1]; i16[u-1] = ti;
          }
        }
      }
    }
    __syncthreads();
  }
  #pragma unroll
  for (int o = 0; o < 16; ++o)
    outidx[(b*SS + orig_s)*KK + o] = i16[o];
}

// ---------------- Transition-down conv + stats + max over K (ptst gather, coalesced) ----------------
__global__ __launch_bounds__(128) void td_kernel(
    const float* __restrict__ ptst,    // [B,N,64] point-major
    const float* __restrict__ xyz,     // [B,3,N]
    const float* __restrict__ newxyz,  // [B,3,S]
    const int* __restrict__ gidx,      // [B,S,K]
    const float* __restrict__ td_w,    // [128,67]
    const float* __restrict__ td_b,    // [128]
    float* __restrict__ ymax,          // [B*S,128]
    float* __restrict__ psum,          // [B*S,128]
    float* __restrict__ psq)
{
  const int bs = blockIdx.x;
  const int b = bs >> 11, s = bs & (SS-1);
  const int t = threadIdx.x;
  __shared__ int gi[KK];
  __shared__ float g[67*17];           // stride 17: conflict-free writes
  if (t < KK) gi[t] = gidx[bs*KK + t];
  __syncthreads();
  #pragma unroll
  for (int base = 0; base < 1024; base += 128) {
    int idx = base + t;
    int i = idx & 63, k = idx >> 6;
    g[i*17 + k] = ptst[(b*NN + gi[k])*64 + i];
  }
  if (t < 48) {
    int c = t >> 4, k = t & 15;
    g[(64+c)*17 + k] = xyz[(b*3+c)*NN + gi[k]] - newxyz[(b*3+c)*SS + s];
  }
  __syncthreads();
  float acc[KK];
  #pragma unroll
  for (int k = 0; k < KK; ++k) acc[k] = 0.0f;
  const float* wrow = td_w + t*67;
  for (int i = 0; i < 67; ++i) {
    float w = wrow[i];
    #pragma unroll
    for (int k = 0; k < KK; ++k) acc[k] = fmaf(w, g[i*17 + k], acc[k]);
  }
  float bias = td_b[t];
  float mx = -1e30f, s1 = 0.f, s2 = 0.f;
  #pragma unroll
  for (int k = 0; k < KK; ++k) {
    float y = acc[k] + bias;
    mx = fmaxf(mx, y);
    s1 += y;
    s2 = fmaf(y, y, s2);
  }
  ymax[bs*128 + t] = mx;             // coalesced
  psum[bs*128 + t] = s1;             // coalesced
  psq [bs*128 + t] = s2;             // coalesced
}

// ---------------- bn_partial + fused bn_final (last-block trick; counter zeroed by fps launch) ----------------
__global__ __launch_bounds__(256) void bn_partial(
    const float* __restrict__ psum, const float* __restrict__ psq,
    float* __restrict__ part1, float* __restrict__ part2,
    const float* __restrict__ gamma, const float* __restrict__ beta,
    float* __restrict__ scale, float* __restrict__ bias,
    int* __restrict__ counter)
{
  const int blk = blockIdx.x, t = threadIdx.x;
  const int c = t & 127, half = t >> 7;
  const float* ps = psum + (blk*64 + half*32)*128;
  const float* pq = psq  + (blk*64 + half*32)*128;
  float s1 = 0.f, s2 = 0.f;
  for (int r = 0; r < 32; ++r) { s1 += ps[r*128 + c]; s2 += pq[r*128 + c]; }
  __shared__ float sh1[256], sh2[256];
  __shared__ int s_last;
  sh1[t] = s1; sh2[t] = s2;
  __syncthreads();
  if (t < 128) {
    part1[blk*128 + t] = sh1[t] + sh1[t+128];
    part2[blk*128 + t] = sh2[t] + sh2[t+128];
  }
  __syncthreads();
  __threadfence();
  if (t == 0) s_last = (atomicAdd(counter, 1) == 127) ? 1 : 0;
  __syncthreads();
  if (!s_last) return;
  __threadfence();
  float f1 = 0.f, f2 = 0.f;
  for (int j = half*64; j < half*64 + 64; ++j) {
    f1 += part1[j*128 + c];
    f2 += part2[j*128 + c];
  }
  sh1[t] = f1; sh2[t] = f2;
  __syncthreads();
  if (t < 128) {
    float a1 = sh1[t] + sh1[t+128];
    float a2 = sh2[t] + sh2[t+128];
    const float n = (float)(BB*SS*KK);
    float mean = a1/n;
    float var  = a2/n - mean*mean;
    float sc = gamma[t] / sqrtf(var + 1e-5f);
    scale[t] = sc;
    bias[t]  = beta[t] - mean*sc;
  }
}

// ---------------- r1_first: fused td_final + r1 (i=0) ----------------
__global__ __launch_bounds__(128) void r1_first(
    const float* __restrict__ ymax,   // [B*S,128]
    const float* __restrict__ scale, const float* __restrict__ bias,
    const float* __restrict__ bw, const float* __restrict__ bb,   // [32,128],[32]
    const float* __restrict__ qw,                                 // [96,32]
    float* __restrict__ pts,          // [B*S,128] (written here)
    float* __restrict__ qkv)
{
  const int bs = blockIdx.x;
  const int t = threadIdx.x;
  __shared__ float pcol[128];
  __shared__ float p[32];
  float v = fmaxf(fmaf(ymax[bs*128 + t], scale[t], bias[t]), 0.0f);
  pts[bs*128 + t] = v;
  pcol[t] = v;
  __syncthreads();
  if (t < 32) {
    float acc = 0.f;
    const float* w = bw + t*128;
    for (int j = 0; j < 128; ++j) acc = fmaf(w[j], pcol[j], acc);
    p[t] = acc + bb[t];
  }
  __syncthreads();
  if (t < 96) {
    float acc = 0.f;
    const float* w = qw + t*32;
    #pragma unroll
    for (int j = 0; j < 32; ++j) acc = fmaf(w[j], p[j], acc);
    qkv[bs*96 + t] = acc;
  }
}

// ---------------- Res block part 1 (pts [B*S,128], qkv [B*S,96]) ----------------
__global__ __launch_bounds__(128) void r1_kernel(
    const float* __restrict__ pts,
    const float* __restrict__ bw, const float* __restrict__ bb,   // [32,128],[32]
    const float* __restrict__ qw,                                 // [96,32]
    float* __restrict__ qkv)
{
  const int bs = blockIdx.x;
  const int t = threadIdx.x;
  __shared__ float pcol[128];
  __shared__ float p[32];
  pcol[t] = pts[bs*128 + t];
  __syncthreads();
  if (t < 32) {
    float acc = 0.f;
    const float* w = bw + t*128;
    for (int j = 0; j < 128; ++j) acc = fmaf(w[j], pcol[j], acc);
    p[t] = acc + bb[t];
  }
  __syncthreads();
  if (t < 96) {
    float acc = 0.f;
    const float* w = qw + t*32;
    #pragma unroll
    for (int j = 0; j < 32; ++j) acc = fmaf(w[j], p[j], acc);
    qkv[bs*96 + t] = acc;
  }
}

// ---------------- Res block part 2; outT!=null => write final transposed to [B,128,S] ----------------
__global__ __launch_bounds__(128) void r2_kernel(
    const float* __restrict__ qkv,
    const float* __restrict__ newxyz, // [B,3,S]
    const int* __restrict__ sgidx,    // [B,S,K]
    const float* __restrict__ pw1, const float* __restrict__ pb1,  // [64,3],[64]
    const float* __restrict__ pw2, const float* __restrict__ pb2,  // [32,64],[32]
    const float* __restrict__ aw1, const float* __restrict__ ab1,  // [128,32],[128]
    const float* __restrict__ aw2, const float* __restrict__ ab2,  // [32,128],[32]
    const float* __restrict__ fw,  const float* __restrict__ fb,   // [128,32],[128]
    float* __restrict__ pts,          // [B*S,128]  (+= when outT==null)
    float* __restrict__ outT)         // [B,128,S] or null
{
  const int bs = blockIdx.x;
  const int b = bs >> 11, s = bs & (SS-1);
  const int t = threadIdx.x;
  __shared__ int sgi[KK];
  __shared__ float qv[32];
  __shared__ float kn[32*17], vn[32*17];   // stride 17: conflict-free
  __shared__ float gx[3*KK];
  __shared__ float h1[64*KK];
  __shared__ float x2[32*KK];
  __shared__ float a1[128*17];             // stride 17
  __shared__ float simb[32*KK];
  __shared__ float agg[32];
  if (t < KK) sgi[t] = sgidx[bs*KK + t];
  __syncthreads();
  if (t < 32) qv[t] = qkv[bs*96 + t];
  for (int idx = t; idx < 32*KK; idx += 128) {
    int k = idx >> 5, c = idx & 31;
    int base = (b*SS + sgi[k])*96;
    kn[c*17+k] = qkv[base + 32 + c];
    vn[c*17+k] = qkv[base + 64 + c];
  }
  if (t < 3*KK) {
    int c = t >> 4, k = t & 15;
    gx[t] = newxyz[(b*3+c)*SS + s] - newxyz[(b*3+c)*SS + sgi[k]];
  }
  __syncthreads();
  for (int idx = t; idx < 64*KK; idx += 128) {
    int c = idx >> 4, k = idx & 15;
    float acc = 0.f;
    #pragma unroll
    for (int j = 0; j < 3; ++j) acc = fmaf(pw1[c*3+j], gx[j*KK+k], acc);
    h1[idx] = fmaxf(acc + pb1[c], 0.0f);
  }
  __syncthreads();
  for (int idx = t; idx < 32*KK; idx += 128) {
    int c = idx >> 4, k = idx & 15;
    float acc = 0.f;
    const float* w = pw2 + c*64;
    for (int j = 0; j < 64; ++j) acc = fmaf(w[j], h1[j*KK+k], acc);
    float r = acc + pb2[c];
    x2[idx] = (qv[c] - kn[c*17+k]) + r;   // qk_rel + rel
    vn[c*17+k] = vn[c*17+k] + r;          // v + rel
  }
  __syncthreads();
  {
    float acc[KK];
    #pragma unroll
    for (int k = 0; k < KK; ++k) acc[k] = 0.f;
    const float* w = aw1 + t*32;
    for (int j = 0; j < 32; ++j) {
      float wv = w[j];
      #pragma unroll
      for (int k = 0; k < KK; ++k) acc[k] = fmaf(wv, x2[j*KK+k], acc[k]);
    }
    float bv = ab1[t];
    #pragma unroll
    for (int k = 0; k < KK; ++k) a1[t*17+k] = fmaxf(acc[k] + bv, 0.0f);
  }
  __syncthreads();
  for (int idx = t; idx < 32*KK; idx += 128) {
    int c = idx >> 4, k = idx & 15;
    float acc = 0.f;
    const float* w = aw2 + c*128;
    for (int j = 0; j < 128; ++j) acc = fmaf(w[j], a1[j*17+k], acc);
    simb[idx] = acc + ab2[c];
  }
  __syncthreads();
  if (t < 32) {
    float m = -1e30f;
    #pragma unroll
    for (int k = 0; k < KK; ++k) m = fmaxf(m, simb[t*KK+k]);
    float sum = 0.f;
    float e[KK];
    #pragma unroll
    for (int k = 0; k < KK; ++k) { e[k] = __expf(simb[t*KK+k] - m); sum += e[k]; }
    float inv = 1.0f / sum;
    float a = 0.f;
    #pragma unroll
    for (int k = 0; k < KK; ++k) a = fmaf(e[k]*inv, vn[t*17+k], a);
    agg[t] = a;
  }
  __syncthreads();
  {
    float acc = 0.f;
    const float* w = fw + t*32;
    #pragma unroll
    for (int j = 0; j < 32; ++j) acc = fmaf(w[j], agg[j], acc);
    float val = pts[bs*128 + t] + (acc + fb[t]);
    if (outT) outT[(b*128 + t)*SS + s] = val;
    else      pts[bs*128 + t] = val;
  }
}

extern "C" void kernel_launch(void* const* d_in, const int* in_sizes, int n_in,
                              void* d_out, int out_size, void* d_ws, size_t ws_size,
                              hipStream_t stream) {
  const float* xyz      = (const float*)d_in[0];
  const float* points   = (const float*)d_in[1];
  const float* td_w     = (const float*)d_in[2];
  const float* td_b     = (const float*)d_in[3];
  const float* td_gamma = (const float*)d_in[4];
  const float* td_beta  = (const float*)d_in[5];
  const float* bw  = (const float*)d_in[6];
  const float* bb  = (const float*)d_in[7];
  const float* qw  = (const float*)d_in[8];
  const float* pw1 = (const float*)d_in[9];
  const float* pb1 = (const float*)d_in[10];
  const float* pw2 = (const float*)d_in[11];
  const float* pb2 = (const float*)d_in[12];
  const float* aw1 = (const float*)d_in[13];
  const float* ab1 = (const float*)d_in[14];
  const float* aw2 = (const float*)d_in[15];
  const float* ab2 = (const float*)d_in[16];
  const float* fw  = (const float*)d_in[17];
  const float* fb  = (const float*)d_in[18];
  float* out = (float*)d_out;
  float* out_newxyz = out;                 // [B,3,S]
  float* out_pts    = out + BB*3*SS;       // [B,128,S]

  char* w = (char*)d_ws;
  int*   gidx   = (int*)w;   w += BB*SS*KK*sizeof(int);
  int*   sgidx  = (int*)w;   w += BB*SS*KK*sizeof(int);
  float* ymax   = (float*)w; w += BB*128*SS*sizeof(float);
  float* psum   = (float*)w; w += 128*BB*SS*sizeof(float);
  float* psq    = (float*)w; w += 128*BB*SS*sizeof(float);
  float* part1  = (float*)w; w += 128*128*sizeof(float);
  float* part2  = (float*)w; w += 128*128*sizeof(float);
  float* bnscale= (float*)w; w += 256*sizeof(float);
  float* bnbias = (float*)w; w += 256*sizeof(float);
  float* pts    = (float*)w; w += BB*128*SS*sizeof(float);
  float* qkv    = (float*)w; w += BB*96*SS*sizeof(float);
  float* ptst   = (float*)w; w += BB*NN*64*sizeof(float);   // [B,N,64]
  int*   flags  = (int*)w;   w += 256;   // [0]=spinner release, [8]=bn counter
  float4* csorted = (float4*)w; w += BB*NN*sizeof(float4);  // 512 KB
  float*  caabb   = (float*)w;  w += BB*32*8*sizeof(float);
  float4* qsorted = (float4*)w; w += BB*SS*sizeof(float4);  // 128 KB
  float*  qaabb   = (float*)w;  w += BB*8*8*sizeof(float);

  fps_kernel<<<BB + TRB + SPB, FTH, 0, stream>>>(xyz, points, out_newxyz, ptst,
      csorted, caabb, qsorted, qaabb, flags);
  knn_kernel<<<256, 64, 0, stream>>>(qsorted, qaabb, csorted, caabb, gidx, sgidx);
  td_kernel<<<BB*SS, 128, 0, stream>>>(ptst, xyz, out_newxyz, gidx, td_w, td_b, ymax, psum, psq);
  bn_partial<<<128, 256, 0, stream>>>(psum, psq, part1, part2,
      td_gamma, td_beta, bnscale, bnbias, &flags[8]);
  r1_first<<<BB*SS, 128, 0, stream>>>(ymax, bnscale, bnbias, bw, bb, qw, pts, qkv);
  r2_kernel<<<BB*SS, 128, 0, stream>>>(qkv, out_newxyz, sgidx,
      pw1, pb1, pw2, pb2, aw1, ab1, aw2, ab2, fw, fb, pts, nullptr);
  r1_kernel<<<BB*SS, 128, 0, stream>>>(pts, bw + 32*128, bb + 32, qw + 96*32, qkv);
  r2_kernel<<<BB*SS, 128, 0, stream>>>(qkv, out_newxyz, sgidx,
      pw1 + 64*3, pb1 + 64, pw2 + 32*64, pb2 + 32,
      aw1 + 128*32, ab1 + 128, aw2 + 32*128, ab2 + 32,
      fw + 128*32, fb + 128, pts, out_pts);
}

// Round 10
// 2308.173 us; speedup vs baseline: 1.2462x; 1.2462x over previous
//
#include <hip/hip_runtime.h>

#define BB 4
#define NN 8192
#define SS 2048
#define KK 16

typedef float v2f __attribute__((ext_vector_type(2)));

// R20: hybrid KNN = R8's verified 8-wave/merge structure + R19's verified sorted slices/AABBs.
// R19 post-mortem: pruning worked but 1-wave blocks collapsed occupancy 8x and __all(skip) over wide
// query groups rarely fired -> 2.6x slower. Here: block = 64 SORTED queries, 8 waves split the 32 candidate
// slices (4/wave; self-half: 1/wave) in zigzag-proximity rank order (wave's first slice = its nearest).
// After the first slice fills top-16, later slices skip vs the wave's OWN theta: exact (skipped cand has
// d2 >= lb*(1-eps) > theta_wave >= wave's 16th-best -> can't enter wave list -> can't affect merge).
// Per-wave private LDS staging (no cross-wave sharing) -> zero barriers in the scan loop. Merge verbatim R8.
__device__ __forceinline__ float wred_max(float v) {
  float s;
  s = __int_as_float(__builtin_amdgcn_update_dpp(0, __float_as_int(v), 0x111, 0xf, 0xf, true)); v = fmaxf(v, s);
  s = __int_as_float(__builtin_amdgcn_update_dpp(0, __float_as_int(v), 0x112, 0xf, 0xf, true)); v = fmaxf(v, s);
  s = __int_as_float(__builtin_amdgcn_update_dpp(0, __float_as_int(v), 0x114, 0xf, 0xf, true)); v = fmaxf(v, s);
  s = __int_as_float(__builtin_amdgcn_update_dpp(0, __float_as_int(v), 0x118, 0xf, 0xf, true)); v = fmaxf(v, s);
  s = __int_as_float(__builtin_amdgcn_update_dpp(0, __float_as_int(v), 0x142, 0xf, 0xf, true)); v = fmaxf(v, s);
  s = __int_as_float(__builtin_amdgcn_update_dpp(0, __float_as_int(v), 0x143, 0xf, 0xf, true)); v = fmaxf(v, s);
  return v;   // lane63 = wave max; 0-fill only widens boxes (safe for AABB use)
}
__device__ __forceinline__ float wred_min(float v) {
  float s;
  s = __int_as_float(__builtin_amdgcn_update_dpp(0, __float_as_int(v), 0x111, 0xf, 0xf, true)); v = fminf(v, s);
  s = __int_as_float(__builtin_amdgcn_update_dpp(0, __float_as_int(v), 0x112, 0xf, 0xf, true)); v = fminf(v, s);
  s = __int_as_float(__builtin_amdgcn_update_dpp(0, __float_as_int(v), 0x114, 0xf, 0xf, true)); v = fminf(v, s);
  s = __int_as_float(__builtin_amdgcn_update_dpp(0, __float_as_int(v), 0x118, 0xf, 0xf, true)); v = fminf(v, s);
  s = __int_as_float(__builtin_amdgcn_update_dpp(0, __float_as_int(v), 0x142, 0xf, 0xf, true)); v = fminf(v, s);
  s = __int_as_float(__builtin_amdgcn_update_dpp(0, __float_as_int(v), 0x143, 0xf, 0xf, true)); v = fminf(v, s);
  return v;
}
__device__ __forceinline__ int morton8(float x, float y, float z,
                                       float mnx, float mny, float mnz,
                                       float scx, float scy, float scz) {
  int qx = min(7, (int)((x - mnx) * scx));
  int qy = min(7, (int)((y - mny) * scy));
  int qz = min(7, (int)((z - mnz) * scz));
  return (qx&1) | ((qy&1)<<1) | ((qz&1)<<2)
       | ((qx&2)<<2) | ((qy&2)<<3) | ((qz&2)<<4)
       | ((qx&4)<<4) | ((qy&4)<<5) | ((qz&4)<<6);
}

#define FTH 512
#define FPT (NN/FTH)  // 16 points per thread
#define TRB 256       // transpose blocks
#define SPB 124       // spinner blocks
__global__ __launch_bounds__(FTH, 1) void fps_kernel(
    const float* __restrict__ xyz,    // [B,3,N]
    const float* __restrict__ points, // [B,64,N]
    float* __restrict__ out_newxyz,   // [B,3,S]
    float* __restrict__ ptst,         // [B,N,64]
    float4* __restrict__ csorted,     // [B][8192] sorted candidates (x,y,z,origidx)
    float*  __restrict__ caabb,       // [B][32][8] slice AABBs
    float4* __restrict__ qsorted,     // [B][2048] sorted queries (x,y,z,orig_s)
    float*  __restrict__ qaabb,       // [B][8][8]
    int* __restrict__ spin_flag)
{
  #pragma clang fp contract(off)
  const int blk = blockIdx.x;
  const int tid = threadIdx.x;
  const int wave = tid >> 6;
  const int lane = tid & 63;
  __shared__ __align__(16) float4 sxyz[NN];                // 128 KB sorted points
  __shared__ __align__(16) unsigned long long skey[2][8];  // per-wave packed (maxdist,~idx), dbuf
  __shared__ int smi[SS];                                  // scan scratch / winner history
  __shared__ float sred[8*6];                              // per-wave bbox partials
  __shared__ float tile[32][33];                           // transpose-role tile

  if (blk >= BB) {
    if (blk < BB + TRB) {
      // ---------- transpose role: points [B,64,N] -> ptst [B,N,64], 8 tiles of 32x32 ----------
      if (blk == BB && tid == 0) spin_flag[8] = 0;         // zero bn-fusion counter
      const int x = tid & 31, yy = tid >> 5;               // 32 x 16
      for (int q = 0; q < 8; ++q) {
        const int tj = (blk - BB)*8 + q;                   // [0, 2048)
        const int tn = tj & 255, tc = (tj >> 8) & 1, tb = tj >> 9;
        const int n0 = tn*32, c0 = tc*32;
        __syncthreads();
        tile[yy][x]    = points[(tb*64 + c0+yy)*NN + n0+x];
        tile[yy+16][x] = points[(tb*64 + c0+yy+16)*NN + n0+x];
        __syncthreads();
        ptst[(tb*NN + n0+yy)*64 + c0+x]    = tile[x][yy];
        ptst[(tb*NN + n0+yy+16)*64 + c0+x] = tile[x][yy+16];
      }
      if (blk - BB < BB) {
        // ---------- candidate-structure builder (hidden under fps's ~1.5ms): batch b2 ----------
        const int b2 = blk - BB;
        const float* xb2 = xyz + b2*3*NN;
        float tx[FPT], ty[FPT], tz[FPT];
        #pragma unroll
        for (int j = 0; j < FPT; ++j) {
          int i = tid + j*FTH;
          tx[j] = xb2[i]; ty[j] = xb2[NN+i]; tz[j] = xb2[2*NN+i];
        }
        float mnx = tx[0], mxx = tx[0], mny = ty[0], mxy = ty[0], mnz = tz[0], mxz = tz[0];
        #pragma unroll
        for (int j = 1; j < FPT; ++j) {
          mnx = fminf(mnx, tx[j]); mxx = fmaxf(mxx, tx[j]);
          mny = fminf(mny, ty[j]); mxy = fmaxf(mxy, ty[j]);
          mnz = fminf(mnz, tz[j]); mxz = fmaxf(mxz, tz[j]);
        }
        mnx = wred_min(mnx); mxx = wred_max(mxx);
        mny = wred_min(mny); mxy = wred_max(mxy);
        mnz = wred_min(mnz); mxz = wred_max(mxz);
        if (lane == 63) {
          sred[wave*6+0] = mnx; sred[wave*6+1] = mxx; sred[wave*6+2] = mny;
          sred[wave*6+3] = mxy; sred[wave*6+4] = mnz; sred[wave*6+5] = mxz;
        }
        smi[tid] = 0;
        __syncthreads();
        #pragma unroll
        for (int w = 0; w < 8; ++w) {
          mnx = fminf(mnx, sred[w*6+0]); mxx = fmaxf(mxx, sred[w*6+1]);
          mny = fminf(mny, sred[w*6+2]); mxy = fmaxf(mxy, sred[w*6+3]);
          mnz = fminf(mnz, sred[w*6+4]); mxz = fmaxf(mxz, sred[w*6+5]);
        }
        const float scx = 8.0f / (mxx - mnx + 1e-12f);
        const float scy = 8.0f / (mxy - mny + 1e-12f);
        const float scz = 8.0f / (mxz - mnz + 1e-12f);
        int cells[FPT];
        #pragma unroll
        for (int j = 0; j < FPT; ++j) {
          cells[j] = morton8(tx[j], ty[j], tz[j], mnx, mny, mnz, scx, scy, scz);
          atomicAdd(&smi[cells[j]], 1);
        }
        __syncthreads();
        for (int d = 1; d < 512; d <<= 1) {
          int v = smi[tid];
          int a = (tid >= d) ? smi[tid - d] : 0;
          __syncthreads();
          smi[tid] = v + a;
          __syncthreads();
        }
        { int excl = (tid == 0) ? 0 : smi[tid - 1]; smi[512 + tid] = excl; }
        __syncthreads();
        #pragma unroll
        for (int j = 0; j < FPT; ++j) {
          int pos = atomicAdd(&smi[512 + cells[j]], 1);
          csorted[b2*NN + pos] = make_float4(tx[j], ty[j], tz[j], __int_as_float(tid + j*FTH));
        }
        __syncthreads();   // drain scatter (same-CU L2 reads below are then coherent)
        // slice AABBs: wave w handles slices w, w+8, w+16, w+24 (256 pts each; 4/lane)
        for (int sl = wave; sl < 32; sl += 8) {
          float a0x=1e30f, a1x=-1e30f, a0y=1e30f, a1y=-1e30f, a0z=1e30f, a1z=-1e30f;
          #pragma unroll
          for (int t = 0; t < 4; ++t) {
            float4 c = csorted[b2*NN + sl*256 + lane*4 + t];
            a0x = fminf(a0x, c.x); a1x = fmaxf(a1x, c.x);
            a0y = fminf(a0y, c.y); a1y = fmaxf(a1y, c.y);
            a0z = fminf(a0z, c.z); a1z = fmaxf(a1z, c.z);
          }
          a0x = wred_min(a0x); a1x = wred_max(a1x);
          a0y = wred_min(a0y); a1y = wred_max(a1y);
          a0z = wred_min(a0z); a1z = wred_max(a1z);
          if (lane == 63) {
            float* o = caabb + (b2*32 + sl)*8;
            o[0]=a0x; o[1]=a1x; o[2]=a0y; o[3]=a1y; o[4]=a0z; o[5]=a1z;
          }
        }
      }
      return;
    }
    // ---------- spinner role: wave 0 only; FMA activity; exit on fps done ----------
    if (tid >= 64) return;
    const int s0 = atomicAdd(spin_flag, 0);
    float a0 = 1.0f + tid, a1 = 2.0f, a2 = 3.0f, a3 = 4.0f;
    for (int outer = 0; outer < 50000; ++outer) {
      #pragma unroll
      for (int u = 0; u < 256; ++u) {
        a0 = fmaf(a0, 1.0000001f, 1e-7f);
        a1 = fmaf(a1, 0.9999999f, 2e-7f);
        a2 = fmaf(a2, 1.0000002f, 3e-7f);
        a3 = fmaf(a3, 0.9999998f, 4e-7f);
      }
      if (atomicAdd(spin_flag, 0) - s0 >= BB) break;
    }
    asm volatile("" :: "v"(a0), "v"(a1), "v"(a2), "v"(a3));
    return;
  }

  // ---------------- fps role: EXACT R13/R18 structure ----------------
  const int b = blk;
  const float* xb = xyz + b*3*NN;

  float tx[FPT], ty[FPT], tz[FPT];
  #pragma unroll
  for (int j = 0; j < FPT; ++j) {
    int i = tid + j*FTH;
    tx[j] = xb[i]; ty[j] = xb[NN+i]; tz[j] = xb[2*NN+i];
  }
  float mnx = tx[0], mxx = tx[0], mny = ty[0], mxy = ty[0], mnz = tz[0], mxz = tz[0];
  #pragma unroll
  for (int j = 1; j < FPT; ++j) {
    mnx = fminf(mnx, tx[j]); mxx = fmaxf(mxx, tx[j]);
    mny = fminf(mny, ty[j]); mxy = fmaxf(mxy, ty[j]);
    mnz = fminf(mnz, tz[j]); mxz = fmaxf(mxz, tz[j]);
  }
  mnx = wred_min(mnx); mxx = wred_max(mxx);
  mny = wred_min(mny); mxy = wred_max(mxy);
  mnz = wred_min(mnz); mxz = wred_max(mxz);
  if (lane == 63) {
    sred[wave*6+0] = mnx; sred[wave*6+1] = mxx; sred[wave*6+2] = mny;
    sred[wave*6+3] = mxy; sred[wave*6+4] = mnz; sred[wave*6+5] = mxz;
  }
  smi[tid] = 0;                       // zero hist region [0,512)
  __syncthreads();
  #pragma unroll
  for (int w = 0; w < 8; ++w) {
    mnx = fminf(mnx, sred[w*6+0]); mxx = fmaxf(mxx, sred[w*6+1]);
    mny = fminf(mny, sred[w*6+2]); mxy = fmaxf(mxy, sred[w*6+3]);
    mnz = fminf(mnz, sred[w*6+4]); mxz = fmaxf(mxz, sred[w*6+5]);
  }
  const float scx = 8.0f / (mxx - mnx + 1e-12f);
  const float scy = 8.0f / (mxy - mny + 1e-12f);
  const float scz = 8.0f / (mxz - mnz + 1e-12f);
  int cells[FPT];
  #pragma unroll
  for (int j = 0; j < FPT; ++j) {
    cells[j] = morton8(tx[j], ty[j], tz[j], mnx, mny, mnz, scx, scy, scz);
    atomicAdd(&smi[cells[j]], 1);
  }
  __syncthreads();
  for (int d = 1; d < 512; d <<= 1) {
    int v = smi[tid];
    int a = (tid >= d) ? smi[tid - d] : 0;
    __syncthreads();
    smi[tid] = v + a;
    __syncthreads();
  }
  {
    int excl = (tid == 0) ? 0 : smi[tid - 1];
    smi[512 + tid] = excl;
  }
  __syncthreads();
  #pragma unroll
  for (int j = 0; j < FPT; ++j) {
    int pos = atomicAdd(&smi[512 + cells[j]], 1);
    sxyz[pos] = make_float4(tx[j], ty[j], tz[j], 0.0f);
  }
  __syncthreads();
  v2f px[FPT/2], py[FPT/2], pz[FPT/2], dist[FPT/2];
  float bx0, bx1, by0, by1, bz0, bz1;
  {
    float4 c0 = sxyz[tid*FPT];
    bx0 = bx1 = c0.x; by0 = by1 = c0.y; bz0 = bz1 = c0.z;
    #pragma unroll
    for (int e = 0; e < FPT; ++e) {
      float4 cc = sxyz[tid*FPT + e];
      ((float*)px)[e] = cc.x; ((float*)py)[e] = cc.y; ((float*)pz)[e] = cc.z;
      ((float*)dist)[e] = 1e10f;
      bx0 = fminf(bx0, cc.x); bx1 = fmaxf(bx1, cc.x);
      by0 = fminf(by0, cc.y); by1 = fmaxf(by1, cc.y);
      bz0 = fminf(bz0, cc.z); bz1 = fmaxf(bz1, cc.z);
    }
  }
  float dmax = 1e10f;
  int   beste = 0;
  float cx = xb[0], cy = xb[NN], cz = xb[2*NN];   // iteration-0 centroid = ORIGINAL point 0
  __syncthreads();
  for (int it = 1; it < SS; ++it) {
    const int buf = it & 1;
    float gx = fmaxf(fmaxf(bx0 - cx, cx - bx1), 0.0f);
    float gy = fmaxf(fmaxf(by0 - cy, cy - by1), 0.0f);
    float gz = fmaxf(fmaxf(bz0 - cz, cz - bz1), 0.0f);
    float lb = gx*gx + gy*gy; lb = lb + gz*gz;
    if (lb * 0.99999f < dmax) {
      v2f cx2 = {cx, cx}, cy2 = {cy, cy}, cz2 = {cz, cz};
      v2f vmax = {-1.0f, -1.0f};
      #pragma unroll
      for (int j = 0; j < FPT/2; ++j) {
        v2f dx = px[j] - cx2, dy = py[j] - cy2, dz = pz[j] - cz2;
        v2f d = dx*dx + dy*dy;
        d = d + dz*dz;
        v2f nd = __builtin_elementwise_min(dist[j], d);
        dist[j] = nd;
        vmax = __builtin_elementwise_max(vmax, nd);
      }
      float mloc = fmaxf(vmax.x, vmax.y);
      int ce[FPT/2];
      #pragma unroll
      for (int j = 0; j < FPT/2; ++j) {
        int c = 0x7FFFFFFF;
        if (dist[j].y == mloc) c = 2*j + 1;
        if (dist[j].x == mloc) c = 2*j;
        ce[j] = c;
      }
      #pragma unroll
      for (int st = FPT/4; st >= 1; st >>= 1) {
        #pragma unroll
        for (int j = 0; j < st; ++j) ce[j] = ce[j] < ce[j+st] ? ce[j] : ce[j+st];
      }
      dmax = mloc;
      beste = ce[0];
    }
    // R18 wave argmax: f32 max ladder + ballot + readlane (verified)
    float wm = dmax;
    wm = wred_max(wm);
    wm = __int_as_float(__builtin_amdgcn_readlane(__float_as_int(wm), 63));
    unsigned long long em = __ballot(dmax == wm);
    int lw = (int)__ffsll((unsigned long long)em) - 1;
    int bi_w = __builtin_amdgcn_readlane((tid << 4) + beste, lw);
    if (lane == 63) skey[buf][wave] = ((unsigned long long)__float_as_uint(wm) << 32) | (unsigned)~bi_w;
    __syncthreads();
    const ulonglong2* kp = (const ulonglong2*)&skey[buf][0];
    ulonglong2 k01 = kp[0], k23 = kp[1], k45 = kp[2], k67 = kp[3];
    unsigned long long m0 = k01.x > k01.y ? k01.x : k01.y;
    unsigned long long m1 = k23.x > k23.y ? k23.x : k23.y;
    unsigned long long m2 = k45.x > k45.y ? k45.x : k45.y;
    unsigned long long m3 = k67.x > k67.y ? k67.x : k67.y;
    unsigned long long ma = m0 > m1 ? m0 : m1;
    unsigned long long mb = m2 > m3 ? m2 : m3;
    unsigned long long mk = ma > mb ? ma : mb;
    int mi = (int)(~(unsigned)mk);
    float4 c = sxyz[mi];
    if (tid == 0) smi[it] = mi;
    cx = c.x; cy = c.y; cz = c.z;
  }
  __syncthreads();
  // epilogue: write sampled coords; it=0 from ORIGINAL point 0
  for (int it = tid; it < SS; it += FTH) {
    float x, y, z;
    if (it == 0) { x = xb[0]; y = xb[NN]; z = xb[2*NN]; }
    else { float4 c = sxyz[smi[it]]; x = c.x; y = c.y; z = c.z; }
    out_newxyz[(b*3+0)*SS + it] = x;
    out_newxyz[(b*3+1)*SS + it] = y;
    out_newxyz[(b*3+2)*SS + it] = z;
  }
  // ---- Morton-sort the 2048 samples -> qsorted (+orig s), 8 slice AABBs -> qaabb (verified R19) ----
  float4 qp4[4]; int qj4[4], qc4[4];
  #pragma unroll
  for (int k2 = 0; k2 < 4; ++k2) {
    int j = tid + k2*FTH;
    float4 p;
    if (j == 0) p = make_float4(xb[0], xb[NN], xb[2*NN], 0.0f);
    else        p = sxyz[smi[j]];
    qp4[k2] = p; qj4[k2] = j;
  }
  __syncthreads();            // done reading smi history
  smi[tid] = 0;
  __syncthreads();
  #pragma unroll
  for (int k2 = 0; k2 < 4; ++k2) {
    qc4[k2] = morton8(qp4[k2].x, qp4[k2].y, qp4[k2].z, mnx, mny, mnz, scx, scy, scz);
    atomicAdd(&smi[qc4[k2]], 1);
  }
  __syncthreads();
  for (int d = 1; d < 512; d <<= 1) {
    int v = smi[tid];
    int a = (tid >= d) ? smi[tid - d] : 0;
    __syncthreads();
    smi[tid] = v + a;
    __syncthreads();
  }
  { int excl = (tid == 0) ? 0 : smi[tid - 1]; smi[512 + tid] = excl; }
  __syncthreads();
  #pragma unroll
  for (int k2 = 0; k2 < 4; ++k2) {
    int pos = atomicAdd(&smi[512 + qc4[k2]], 1);
    qsorted[b*SS + pos] = make_float4(qp4[k2].x, qp4[k2].y, qp4[k2].z, __int_as_float(qj4[k2]));
  }
  __syncthreads();            // drain scatter; same-CU reads below coherent
  {
    float a0x=1e30f, a1x=-1e30f, a0y=1e30f, a1y=-1e30f, a0z=1e30f, a1z=-1e30f;
    #pragma unroll
    for (int t = 0; t < 4; ++t) {
      float4 c = qsorted[b*SS + wave*256 + lane*4 + t];
      a0x = fminf(a0x, c.x); a1x = fmaxf(a1x, c.x);
      a0y = fminf(a0y, c.y); a1y = fmaxf(a1y, c.y);
      a0z = fminf(a0z, c.z); a1z = fmaxf(a1z, c.z);
    }
    a0x = wred_min(a0x); a1x = wred_max(a1x);
    a0y = wred_min(a0y); a1y = wred_max(a1y);
    a0z = wred_min(a0z); a1z = wred_max(a1z);
    if (lane == 63) {
      float* o = qaabb + (b*8 + wave)*8;
      o[0]=a0x; o[1]=a1x; o[2]=a0y; o[3]=a1y; o[4]=a0z; o[5]=a1z;
    }
  }
  if (tid == 0) atomicAdd(spin_flag, 1);   // release spinners
}

// ---------------- KNN: block = 64 sorted queries, 8 waves split slices (zigzag rank), per-wave theta skip ----------------
#define KTH 512
__global__ __launch_bounds__(KTH) void knn_kernel(
    const float4* __restrict__ qsorted, // [B][2048]
    const float*  __restrict__ qaabb,   // [B][8][8]
    const float4* __restrict__ csorted, // [B][8192]
    const float*  __restrict__ caabb,   // [B][32][8]
    int* __restrict__ out1,             // [B,S,K] vs xyz (orig indices)
    int* __restrict__ out2)             // [B,S,K] self (s indices)
{
  #pragma clang fp contract(off)
  __shared__ float4 sc[8][256];          // per-wave slice staging (32 KB)
  __shared__ int    sidx[8][256];        // 8 KB
  __shared__ float  smd[8*64*17];        // per-wave top-16 dists (pad 17) ~34.8 KB
  __shared__ int    smj[8*64*17];        // per-wave top-16 idxs
  const int bid = blockIdx.x;
  const int half = bid >> 7;             // 0: vs xyz, 1: self
  const int rem = bid & 127;
  const int b = rem >> 5;
  const int wslot = rem & 31;            // sorted-query group
  const int wave = threadIdx.x >> 6, lane = threadIdx.x & 63;
  const float4* cand = half ? (qsorted + b*SS) : (csorted + b*NN);
  const float*  aabb = half ? (qaabb + b*8*8) : (caabb + b*32*8);
  const int nsl = half ? 8 : 32;
  const int sh = half ? (wslot >> 2) : wslot;   // home slice
  const int nj = nsl >> 3;               // slices per wave: 4 (NN) / 1 (self)
  int* outidx = half ? out2 : out1;

  // all 8 waves load the SAME 64 sorted queries
  float4 q = qsorted[b*SS + wslot*64 + lane];
  const int orig_s = __float_as_int(q.w);
  const float qx = q.x, qy = q.y, qz = q.z;
  float sq = qx*qx + qy*qy; sq = sq + qz*qz;
  float d16[16]; int i16[16];
  #pragma unroll
  for (int j = 0; j < 16; ++j) { d16[j] = 1e30f; i16[j] = 0x7FFFFFFF; }

  for (int jj = 0; jj < nj; ++jj) {
    const int j = wave + jj*8;           // zigzag rank: wave's first slice is its nearest
    const int off = (j + 1) >> 1;
    const int s = (sh + ((j & 1) ? off : -off)) & (nsl - 1);   // distinct mod nsl over j=0..nsl-1
    const float* ab = aabb + s*8;
    // per-lane exact skip vs this wave's own theta (verified R19 margin: false-skip impossible;
    // theta only shrinks -> skip valid at check time is final-valid for the wave's list)
    float gx = fmaxf(fmaxf(ab[0] - qx, qx - ab[1]), 0.0f);
    float gy = fmaxf(fmaxf(ab[2] - qy, qy - ab[3]), 0.0f);
    float gz = fmaxf(fmaxf(ab[4] - qz, qz - ab[5]), 0.0f);
    float lbnd = gx*gx + gy*gy; lbnd = lbnd + gz*gz;
    bool skip = (lbnd * 0.9999f - 1e-3f) > d16[15];
    if (__all(skip)) continue;
    // stage slice s into this wave's private LDS region (wave-synchronous; no barrier needed)
    #pragma unroll
    for (int t = 0; t < 4; ++t) {
      float4 c = cand[s*256 + t*64 + lane];
      float pp = c.x*c.x + c.y*c.y; pp = pp + c.z*c.z;
      sidx[wave][t*64 + lane] = __float_as_int(c.w);
      sc[wave][t*64 + lane] = make_float4(c.x, c.y, c.z, pp);
    }
    for (int t = 0; t < 256; ++t) {
      float4 c = sc[wave][t];
      float qp = qx*c.x + qy*c.y; qp = qp + qz*c.z;
      float d2 = (sq + c.w) - 2.0f*qp;
      if (d2 < d16[15]) {
        d16[15] = d2; i16[15] = sidx[wave][t];
        #pragma unroll
        for (int u = 15; u > 0; --u) {
          if (d16[u] < d16[u-1]) {
            float td = d16[u]; d16[u] = d16[u-1]; d16[u-1] = td;
            int   ti = i16[u]; i16[u] = i16[u-1]; i16[u-1] = ti;
          }
        }
      }
    }
  }
  const int offm = (wave*64 + lane)*17;
  #pragma unroll
  for (int j = 0; j < 16; ++j) { smd[offm+j] = d16[j]; smj[offm+j] = i16[j]; }
  __syncthreads();
  if (wave == 0) {
    // 8-way stable merge: tie-break on smaller index = stable lax.top_k semantics (verbatim R8)
    int p[8] = {0,0,0,0,0,0,0,0};
    for (int o = 0; o < 16; ++o) {
      float bd = 3e38f; int bi = 0x7FFFFFFF, bw = 0;
      #pragma unroll
      for (int w = 0; w < 8; ++w) {
        float d = smd[(w*64+lane)*17 + p[w]];
        int   i = smj[(w*64+lane)*17 + p[w]];
        if (d < bd || (d == bd && i < bi)) { bd = d; bi = i; bw = w; }
      }
      p[bw]++;
      outidx[(b*SS + orig_s)*KK + o] = bi;
    }
  }
}

// ---------------- Transition-down conv + stats + max over K (ptst gather, coalesced) ----------------
__global__ __launch_bounds__(128) void td_kernel(
    const float* __restrict__ ptst,    // [B,N,64] point-major
    const float* __restrict__ xyz,     // [B,3,N]
    const float* __restrict__ newxyz,  // [B,3,S]
    const int* __restrict__ gidx,      // [B,S,K]
    const float* __restrict__ td_w,    // [128,67]
    const float* __restrict__ td_b,    // [128]
    float* __restrict__ ymax,          // [B*S,128]
    float* __restrict__ psum,          // [B*S,128]
    float* __restrict__ psq)
{
  const int bs = blockIdx.x;
  const int b = bs >> 11, s = bs & (SS-1);
  const int t = threadIdx.x;
  __shared__ int gi[KK];
  __shared__ float g[67*17];           // stride 17: conflict-free writes
  if (t < KK) gi[t] = gidx[bs*KK + t];
  __syncthreads();
  #pragma unroll
  for (int base = 0; base < 1024; base += 128) {
    int idx = base + t;
    int i = idx & 63, k = idx >> 6;
    g[i*17 + k] = ptst[(b*NN + gi[k])*64 + i];
  }
  if (t < 48) {
    int c = t >> 4, k = t & 15;
    g[(64+c)*17 + k] = xyz[(b*3+c)*NN + gi[k]] - newxyz[(b*3+c)*SS + s];
  }
  __syncthreads();
  float acc[KK];
  #pragma unroll
  for (int k = 0; k < KK; ++k) acc[k] = 0.0f;
  const float* wrow = td_w + t*67;
  for (int i = 0; i < 67; ++i) {
    float w = wrow[i];
    #pragma unroll
    for (int k = 0; k < KK; ++k) acc[k] = fmaf(w, g[i*17 + k], acc[k]);
  }
  float bias = td_b[t];
  float mx = -1e30f, s1 = 0.f, s2 = 0.f;
  #pragma unroll
  for (int k = 0; k < KK; ++k) {
    float y = acc[k] + bias;
    mx = fmaxf(mx, y);
    s1 += y;
    s2 = fmaf(y, y, s2);
  }
  ymax[bs*128 + t] = mx;             // coalesced
  psum[bs*128 + t] = s1;             // coalesced
  psq [bs*128 + t] = s2;             // coalesced
}

// ---------------- bn_partial + fused bn_final (last-block trick; counter zeroed by fps launch) ----------------
__global__ __launch_bounds__(256) void bn_partial(
    const float* __restrict__ psum, const float* __restrict__ psq,
    float* __restrict__ part1, float* __restrict__ part2,
    const float* __restrict__ gamma, const float* __restrict__ beta,
    float* __restrict__ scale, float* __restrict__ bias,
    int* __restrict__ counter)
{
  const int blk = blockIdx.x, t = threadIdx.x;
  const int c = t & 127, half = t >> 7;
  const float* ps = psum + (blk*64 + half*32)*128;
  const float* pq = psq  + (blk*64 + half*32)*128;
  float s1 = 0.f, s2 = 0.f;
  for (int r = 0; r < 32; ++r) { s1 += ps[r*128 + c]; s2 += pq[r*128 + c]; }
  __shared__ float sh1[256], sh2[256];
  __shared__ int s_last;
  sh1[t] = s1; sh2[t] = s2;
  __syncthreads();
  if (t < 128) {
    part1[blk*128 + t] = sh1[t] + sh1[t+128];
    part2[blk*128 + t] = sh2[t] + sh2[t+128];
  }
  __syncthreads();
  __threadfence();
  if (t == 0) s_last = (atomicAdd(counter, 1) == 127) ? 1 : 0;
  __syncthreads();
  if (!s_last) return;
  __threadfence();
  float f1 = 0.f, f2 = 0.f;
  for (int j = half*64; j < half*64 + 64; ++j) {
    f1 += part1[j*128 + c];
    f2 += part2[j*128 + c];
  }
  sh1[t] = f1; sh2[t] = f2;
  __syncthreads();
  if (t < 128) {
    float a1 = sh1[t] + sh1[t+128];
    float a2 = sh2[t] + sh2[t+128];
    const float n = (float)(BB*SS*KK);
    float mean = a1/n;
    float var  = a2/n - mean*mean;
    float sc = gamma[t] / sqrtf(var + 1e-5f);
    scale[t] = sc;
    bias[t]  = beta[t] - mean*sc;
  }
}

// ---------------- r1_first: fused td_final + r1 (i=0) ----------------
__global__ __launch_bounds__(128) void r1_first(
    const float* __restrict__ ymax,   // [B*S,128]
    const float* __restrict__ scale, const float* __restrict__ bias,
    const float* __restrict__ bw, const float* __restrict__ bb,   // [32,128],[32]
    const float* __restrict__ qw,                                 // [96,32]
    float* __restrict__ pts,          // [B*S,128] (written here)
    float* __restrict__ qkv)
{
  const int bs = blockIdx.x;
  const int t = threadIdx.x;
  __shared__ float pcol[128];
  __shared__ float p[32];
  float v = fmaxf(fmaf(ymax[bs*128 + t], scale[t], bias[t]), 0.0f);
  pts[bs*128 + t] = v;
  pcol[t] = v;
  __syncthreads();
  if (t < 32) {
    float acc = 0.f;
    const float* w = bw + t*128;
    for (int j = 0; j < 128; ++j) acc = fmaf(w[j], pcol[j], acc);
    p[t] = acc + bb[t];
  }
  __syncthreads();
  if (t < 96) {
    float acc = 0.f;
    const float* w = qw + t*32;
    #pragma unroll
    for (int j = 0; j < 32; ++j) acc = fmaf(w[j], p[j], acc);
    qkv[bs*96 + t] = acc;
  }
}

// ---------------- Res block part 1 (pts [B*S,128], qkv [B*S,96]) ----------------
__global__ __launch_bounds__(128) void r1_kernel(
    const float* __restrict__ pts,
    const float* __restrict__ bw, const float* __restrict__ bb,   // [32,128],[32]
    const float* __restrict__ qw,                                 // [96,32]
    float* __restrict__ qkv)
{
  const int bs = blockIdx.x;
  const int t = threadIdx.x;
  __shared__ float pcol[128];
  __shared__ float p[32];
  pcol[t] = pts[bs*128 + t];
  __syncthreads();
  if (t < 32) {
    float acc = 0.f;
    const float* w = bw + t*128;
    for (int j = 0; j < 128; ++j) acc = fmaf(w[j], pcol[j], acc);
    p[t] = acc + bb[t];
  }
  __syncthreads();
  if (t < 96) {
    float acc = 0.f;
    const float* w = qw + t*32;
    #pragma unroll
    for (int j = 0; j < 32; ++j) acc = fmaf(w[j], p[j], acc);
    qkv[bs*96 + t] = acc;
  }
}

// ---------------- Res block part 2; outT!=null => write final transposed to [B,128,S] ----------------
__global__ __launch_bounds__(128) void r2_kernel(
    const float* __restrict__ qkv,
    const float* __restrict__ newxyz, // [B,3,S]
    const int* __restrict__ sgidx,    // [B,S,K]
    const float* __restrict__ pw1, const float* __restrict__ pb1,  // [64,3],[64]
    const float* __restrict__ pw2, const float* __restrict__ pb2,  // [32,64],[32]
    const float* __restrict__ aw1, const float* __restrict__ ab1,  // [128,32],[128]
    const float* __restrict__ aw2, const float* __restrict__ ab2,  // [32,128],[32]
    const float* __restrict__ fw,  const float* __restrict__ fb,   // [128,32],[128]
    float* __restrict__ pts,          // [B*S,128]  (+= when outT==null)
    float* __restrict__ outT)         // [B,128,S] or null
{
  const int bs = blockIdx.x;
  const int b = bs >> 11, s = bs & (SS-1);
  const int t = threadIdx.x;
  __shared__ int sgi[KK];
  __shared__ float qv[32];
  __shared__ float kn[32*17], vn[32*17];   // stride 17: conflict-free
  __shared__ float gx[3*KK];
  __shared__ float h1[64*KK];
  __shared__ float x2[32*KK];
  __shared__ float a1[128*17];             // stride 17
  __shared__ float simb[32*KK];
  __shared__ float agg[32];
  if (t < KK) sgi[t] = sgidx[bs*KK + t];
  __syncthreads();
  if (t < 32) qv[t] = qkv[bs*96 + t];
  for (int idx = t; idx < 32*KK; idx += 128) {
    int k = idx >> 5, c = idx & 31;
    int base = (b*SS + sgi[k])*96;
    kn[c*17+k] = qkv[base + 32 + c];
    vn[c*17+k] = qkv[base + 64 + c];
  }
  if (t < 3*KK) {
    int c = t >> 4, k = t & 15;
    gx[t] = newxyz[(b*3+c)*SS + s] - newxyz[(b*3+c)*SS + sgi[k]];
  }
  __syncthreads();
  for (int idx = t; idx < 64*KK; idx += 128) {
    int c = idx >> 4, k = idx & 15;
    float acc = 0.f;
    #pragma unroll
    for (int j = 0; j < 3; ++j) acc = fmaf(pw1[c*3+j], gx[j*KK+k], acc);
    h1[idx] = fmaxf(acc + pb1[c], 0.0f);
  }
  __syncthreads();
  for (int idx = t; idx < 32*KK; idx += 128) {
    int c = idx >> 4, k = idx & 15;
    float acc = 0.f;
    const float* w = pw2 + c*64;
    for (int j = 0; j < 64; ++j) acc = fmaf(w[j], h1[j*KK+k], acc);
    float r = acc + pb2[c];
    x2[idx] = (qv[c] - kn[c*17+k]) + r;   // qk_rel + rel
    vn[c*17+k] = vn[c*17+k] + r;          // v + rel
  }
  __syncthreads();
  {
    float acc[KK];
    #pragma unroll
    for (int k = 0; k < KK; ++k) acc[k] = 0.f;
    const float* w = aw1 + t*32;
    for (int j = 0; j < 32; ++j) {
      float wv = w[j];
      #pragma unroll
      for (int k = 0; k < KK; ++k) acc[k] = fmaf(wv, x2[j*KK+k], acc[k]);
    }
    float bv = ab1[t];
    #pragma unroll
    for (int k = 0; k < KK; ++k) a1[t*17+k] = fmaxf(acc[k] + bv, 0.0f);
  }
  __syncthreads();
  for (int idx = t; idx < 32*KK; idx += 128) {
    int c = idx >> 4, k = idx & 15;
    float acc = 0.f;
    const float* w = aw2 + c*128;
    for (int j = 0; j < 128; ++j) acc = fmaf(w[j], a1[j*17+k], acc);
    simb[idx] = acc + ab2[c];
  }
  __syncthreads();
  if (t < 32) {
    float m = -1e30f;
    #pragma unroll
    for (int k = 0; k < KK; ++k) m = fmaxf(m, simb[t*KK+k]);
    float sum = 0.f;
    float e[KK];
    #pragma unroll
    for (int k = 0; k < KK; ++k) { e[k] = __expf(simb[t*KK+k] - m); sum += e[k]; }
    float inv = 1.0f / sum;
    float a = 0.f;
    #pragma unroll
    for (int k = 0; k < KK; ++k) a = fmaf(e[k]*inv, vn[t*17+k], a);
    agg[t] = a;
  }
  __syncthreads();
  {
    float acc = 0.f;
    const float* w = fw + t*32;
    #pragma unroll
    for (int j = 0; j < 32; ++j) acc = fmaf(w[j], agg[j], acc);
    float val = pts[bs*128 + t] + (acc + fb[t]);
    if (outT) outT[(b*128 + t)*SS + s] = val;
    else      pts[bs*128 + t] = val;
  }
}

extern "C" void kernel_launch(void* const* d_in, const int* in_sizes, int n_in,
                              void* d_out, int out_size, void* d_ws, size_t ws_size,
                              hipStream_t stream) {
  const float* xyz      = (const float*)d_in[0];
  const float* points   = (const float*)d_in[1];
  const float* td_w     = (const float*)d_in[2];
  const float* td_b     = (const float*)d_in[3];
  const float* td_gamma = (const float*)d_in[4];
  const float* td_beta  = (const float*)d_in[5];
  const float* bw  = (const float*)d_in[6];
  const float* bb  = (const float*)d_in[7];
  const float* qw  = (const float*)d_in[8];
  const float* pw1 = (const float*)d_in[9];
  const float* pb1 = (const float*)d_in[10];
  const float* pw2 = (const float*)d_in[11];
  const float* pb2 = (const float*)d_in[12];
  const float* aw1 = (const float*)d_in[13];
  const float* ab1 = (const float*)d_in[14];
  const float* aw2 = (const float*)d_in[15];
  const float* ab2 = (const float*)d_in[16];
  const float* fw  = (const float*)d_in[17];
  const float* fb  = (const float*)d_in[18];
  float* out = (float*)d_out;
  float* out_newxyz = out;                 // [B,3,S]
  float* out_pts    = out + BB*3*SS;       // [B,128,S]

  char* w = (char*)d_ws;
  int*   gidx   = (int*)w;   w += BB*SS*KK*sizeof(int);
  int*   sgidx  = (int*)w;   w += BB*SS*KK*sizeof(int);
  float* ymax   = (float*)w; w += BB*128*SS*sizeof(float);
  float* psum   = (float*)w; w += 128*BB*SS*sizeof(float);
  float* psq    = (float*)w; w += 128*BB*SS*sizeof(float);
  float* part1  = (float*)w; w += 128*128*sizeof(float);
  float* part2  = (float*)w; w += 128*128*sizeof(float);
  float* bnscale= (float*)w; w += 256*sizeof(float);
  float* bnbias = (float*)w; w += 256*sizeof(float);
  float* pts    = (float*)w; w += BB*128*SS*sizeof(float);
  float* qkv    = (float*)w; w += BB*96*SS*sizeof(float);
  float* ptst   = (float*)w; w += BB*NN*64*sizeof(float);   // [B,N,64]
  int*   flags  = (int*)w;   w += 256;   // [0]=spinner release, [8]=bn counter
  float4* csorted = (float4*)w; w += BB*NN*sizeof(float4);  // 512 KB
  float*  caabb   = (float*)w;  w += BB*32*8*sizeof(float);
  float4* qsorted = (float4*)w; w += BB*SS*sizeof(float4);  // 128 KB
  float*  qaabb   = (float*)w;  w += BB*8*8*sizeof(float);

  fps_kernel<<<BB + TRB + SPB, FTH, 0, stream>>>(xyz, points, out_newxyz, ptst,
      csorted, caabb, qsorted, qaabb, flags);
  knn_kernel<<<256, KTH, 0, stream>>>(qsorted, qaabb, csorted, caabb, gidx, sgidx);
  td_kernel<<<BB*SS, 128, 0, stream>>>(ptst, xyz, out_newxyz, gidx, td_w, td_b, ymax, psum, psq);
  bn_partial<<<128, 256, 0, stream>>>(psum, psq, part1, part2,
      td_gamma, td_beta, bnscale, bnbias, &flags[8]);
  r1_first<<<BB*SS, 128, 0, stream>>>(ymax, bnscale, bnbias, bw, bb, qw, pts, qkv);
  r2_kernel<<<BB*SS, 128, 0, stream>>>(qkv, out_newxyz, sgidx,
      pw1, pb1, pw2, pb2, aw1, ab1, aw2, ab2, fw, fb, pts, nullptr);
  r1_kernel<<<BB*SS, 128, 0, stream>>>(pts, bw + 32*128, bb + 32, qw + 96*32, qkv);
  r2_kernel<<<BB*SS, 128, 0, stream>>>(qkv, out_newxyz, sgidx,
      pw1 + 64*3, pb1 + 64, pw2 + 32*64, pb2 + 32,
      aw1 + 128*32, ab1 + 128, aw2 + 32*128, ab2 + 32,
      fw + 128*32, fb + 128, pts, out_pts);
}

// Round 11
// 2230.552 us; speedup vs baseline: 1.2896x; 1.0348x over previous
//
#include <hip/hip_runtime.h>

#define BB 4
#define NN 8192
#define SS 2048
#define KK 16

typedef float v2f __attribute__((ext_vector_type(2)));

// R21: weight transposition for coalesced per-thread-row reads (bit-identical math).
// R10 post-mortem: hybrid knn won (2308us). Tail kernels sit 2-3x above VALU floor; common disease =
// per-thread-row weight loads (td_w+t*67, bw+t*128, qw+t*32, aw1+t*32, fw+t*32): each j-load touches
// 64 cache lines. Fix: transpose weights ONCE inside the fps launch (idle worker block, hidden under
// fps's 1.5ms; kernel-boundary ordering publishes to later dispatches). Consumers read wT[j*W+t] ->
// consecutive lanes = consecutive addresses. FMA order/operands unchanged -> bit-identical outputs.
__device__ __forceinline__ float wred_max(float v) {
  float s;
  s = __int_as_float(__builtin_amdgcn_update_dpp(0, __float_as_int(v), 0x111, 0xf, 0xf, true)); v = fmaxf(v, s);
  s = __int_as_float(__builtin_amdgcn_update_dpp(0, __float_as_int(v), 0x112, 0xf, 0xf, true)); v = fmaxf(v, s);
  s = __int_as_float(__builtin_amdgcn_update_dpp(0, __float_as_int(v), 0x114, 0xf, 0xf, true)); v = fmaxf(v, s);
  s = __int_as_float(__builtin_amdgcn_update_dpp(0, __float_as_int(v), 0x118, 0xf, 0xf, true)); v = fmaxf(v, s);
  s = __int_as_float(__builtin_amdgcn_update_dpp(0, __float_as_int(v), 0x142, 0xf, 0xf, true)); v = fmaxf(v, s);
  s = __int_as_float(__builtin_amdgcn_update_dpp(0, __float_as_int(v), 0x143, 0xf, 0xf, true)); v = fmaxf(v, s);
  return v;   // lane63 = wave max; 0-fill only widens boxes (safe for AABB use)
}
__device__ __forceinline__ float wred_min(float v) {
  float s;
  s = __int_as_float(__builtin_amdgcn_update_dpp(0, __float_as_int(v), 0x111, 0xf, 0xf, true)); v = fminf(v, s);
  s = __int_as_float(__builtin_amdgcn_update_dpp(0, __float_as_int(v), 0x112, 0xf, 0xf, true)); v = fminf(v, s);
  s = __int_as_float(__builtin_amdgcn_update_dpp(0, __float_as_int(v), 0x114, 0xf, 0xf, true)); v = fminf(v, s);
  s = __int_as_float(__builtin_amdgcn_update_dpp(0, __float_as_int(v), 0x118, 0xf, 0xf, true)); v = fminf(v, s);
  s = __int_as_float(__builtin_amdgcn_update_dpp(0, __float_as_int(v), 0x142, 0xf, 0xf, true)); v = fminf(v, s);
  s = __int_as_float(__builtin_amdgcn_update_dpp(0, __float_as_int(v), 0x143, 0xf, 0xf, true)); v = fminf(v, s);
  return v;
}
__device__ __forceinline__ int morton8(float x, float y, float z,
                                       float mnx, float mny, float mnz,
                                       float scx, float scy, float scz) {
  int qx = min(7, (int)((x - mnx) * scx));
  int qy = min(7, (int)((y - mny) * scy));
  int qz = min(7, (int)((z - mnz) * scz));
  return (qx&1) | ((qy&1)<<1) | ((qz&1)<<2)
       | ((qx&2)<<2) | ((qy&2)<<3) | ((qz&2)<<4)
       | ((qx&4)<<4) | ((qy&4)<<5) | ((qz&4)<<6);
}

#define FTH 512
#define FPT (NN/FTH)  // 16 points per thread
#define TRB 256       // transpose blocks
#define SPB 124       // spinner blocks
__global__ __launch_bounds__(FTH, 1) void fps_kernel(
    const float* __restrict__ xyz,    // [B,3,N]
    const float* __restrict__ points, // [B,64,N]
    const float* __restrict__ td_w,   // [128,67]
    const float* __restrict__ bw,     // [2,32,128]
    const float* __restrict__ qw,     // [2,96,32]
    const float* __restrict__ aw1,    // [2,128,32]
    const float* __restrict__ fw,     // [2,128,32]
    float* __restrict__ out_newxyz,   // [B,3,S]
    float* __restrict__ ptst,         // [B,N,64]
    float4* __restrict__ csorted,     // [B][8192] sorted candidates (x,y,z,origidx)
    float*  __restrict__ caabb,       // [B][32][8] slice AABBs
    float4* __restrict__ qsorted,     // [B][2048] sorted queries (x,y,z,orig_s)
    float*  __restrict__ qaabb,       // [B][8][8]
    float* __restrict__ td_wT,        // [67][128]
    float* __restrict__ bwT,          // [2][128*32]  (c*32+r)
    float* __restrict__ qwT,          // [2][32*96]   (c*96+r)
    float* __restrict__ aw1T,         // [2][32*128]  (c*128+r)
    float* __restrict__ fwT,          // [2][32*128]
    int* __restrict__ spin_flag)
{
  #pragma clang fp contract(off)
  const int blk = blockIdx.x;
  const int tid = threadIdx.x;
  const int wave = tid >> 6;
  const int lane = tid & 63;
  __shared__ __align__(16) float4 sxyz[NN];                // 128 KB sorted points
  __shared__ __align__(16) unsigned long long skey[2][8];  // per-wave packed (maxdist,~idx), dbuf
  __shared__ int smi[SS];                                  // scan scratch / winner history
  __shared__ float sred[8*6];                              // per-wave bbox partials
  __shared__ float tile[32][33];                           // transpose-role tile

  if (blk >= BB) {
    if (blk < BB + TRB) {
      // ---------- transpose role: points [B,64,N] -> ptst [B,N,64], 8 tiles of 32x32 ----------
      if (blk == BB && tid == 0) spin_flag[8] = 0;         // zero bn-fusion counter
      const int x = tid & 31, yy = tid >> 5;               // 32 x 16
      for (int q = 0; q < 8; ++q) {
        const int tj = (blk - BB)*8 + q;                   // [0, 2048)
        const int tn = tj & 255, tc = (tj >> 8) & 1, tb = tj >> 9;
        const int n0 = tn*32, c0 = tc*32;
        __syncthreads();
        tile[yy][x]    = points[(tb*64 + c0+yy)*NN + n0+x];
        tile[yy+16][x] = points[(tb*64 + c0+yy+16)*NN + n0+x];
        __syncthreads();
        ptst[(tb*NN + n0+yy)*64 + c0+x]    = tile[x][yy];
        ptst[(tb*NN + n0+yy+16)*64 + c0+x] = tile[x][yy+16];
      }
      if (blk == BB + 8) {
        // ---------- weight transposition (one-time, hidden under fps; publishes at kernel boundary) ----------
        for (int idx = tid; idx < 128*67; idx += FTH) {
          int c = idx / 67, i = idx - c*67;                // td_w[c][i]
          td_wT[i*128 + c] = td_w[idx];
        }
        for (int l = 0; l < 2; ++l) {
          for (int idx = tid; idx < 32*128; idx += FTH) {  // bw[l][r<32][c<128]
            int r = idx >> 7, c = idx & 127;
            bwT[l*4096 + c*32 + r] = bw[l*4096 + idx];
          }
          for (int idx = tid; idx < 96*32; idx += FTH) {   // qw[l][r<96][c<32]
            int r = idx >> 5, c = idx & 31;
            qwT[l*3072 + c*96 + r] = qw[l*3072 + idx];
          }
          for (int idx = tid; idx < 128*32; idx += FTH) {  // aw1/fw [l][r<128][c<32]
            int r = idx >> 5, c = idx & 31;
            aw1T[l*4096 + c*128 + r] = aw1[l*4096 + idx];
            fwT [l*4096 + c*128 + r] = fw [l*4096 + idx];
          }
        }
      }
      if (blk - BB < BB) {
        // ---------- candidate-structure builder (hidden under fps's ~1.5ms): batch b2 ----------
        const int b2 = blk - BB;
        const float* xb2 = xyz + b2*3*NN;
        float tx[FPT], ty[FPT], tz[FPT];
        #pragma unroll
        for (int j = 0; j < FPT; ++j) {
          int i = tid + j*FTH;
          tx[j] = xb2[i]; ty[j] = xb2[NN+i]; tz[j] = xb2[2*NN+i];
        }
        float mnx = tx[0], mxx = tx[0], mny = ty[0], mxy = ty[0], mnz = tz[0], mxz = tz[0];
        #pragma unroll
        for (int j = 1; j < FPT; ++j) {
          mnx = fminf(mnx, tx[j]); mxx = fmaxf(mxx, tx[j]);
          mny = fminf(mny, ty[j]); mxy = fmaxf(mxy, ty[j]);
          mnz = fminf(mnz, tz[j]); mxz = fmaxf(mxz, tz[j]);
        }
        mnx = wred_min(mnx); mxx = wred_max(mxx);
        mny = wred_min(mny); mxy = wred_max(mxy);
        mnz = wred_min(mnz); mxz = wred_max(mxz);
        if (lane == 63) {
          sred[wave*6+0] = mnx; sred[wave*6+1] = mxx; sred[wave*6+2] = mny;
          sred[wave*6+3] = mxy; sred[wave*6+4] = mnz; sred[wave*6+5] = mxz;
        }
        smi[tid] = 0;
        __syncthreads();
        #pragma unroll
        for (int w = 0; w < 8; ++w) {
          mnx = fminf(mnx, sred[w*6+0]); mxx = fmaxf(mxx, sred[w*6+1]);
          mny = fminf(mny, sred[w*6+2]); mxy = fmaxf(mxy, sred[w*6+3]);
          mnz = fminf(mnz, sred[w*6+4]); mxz = fmaxf(mxz, sred[w*6+5]);
        }
        const float scx = 8.0f / (mxx - mnx + 1e-12f);
        const float scy = 8.0f / (mxy - mny + 1e-12f);
        const float scz = 8.0f / (mxz - mnz + 1e-12f);
        int cells[FPT];
        #pragma unroll
        for (int j = 0; j < FPT; ++j) {
          cells[j] = morton8(tx[j], ty[j], tz[j], mnx, mny, mnz, scx, scy, scz);
          atomicAdd(&smi[cells[j]], 1);
        }
        __syncthreads();
        for (int d = 1; d < 512; d <<= 1) {
          int v = smi[tid];
          int a = (tid >= d) ? smi[tid - d] : 0;
          __syncthreads();
          smi[tid] = v + a;
          __syncthreads();
        }
        { int excl = (tid == 0) ? 0 : smi[tid - 1]; smi[512 + tid] = excl; }
        __syncthreads();
        #pragma unroll
        for (int j = 0; j < FPT; ++j) {
          int pos = atomicAdd(&smi[512 + cells[j]], 1);
          csorted[b2*NN + pos] = make_float4(tx[j], ty[j], tz[j], __int_as_float(tid + j*FTH));
        }
        __syncthreads();   // drain scatter (same-CU L2 reads below are then coherent)
        // slice AABBs: wave w handles slices w, w+8, w+16, w+24 (256 pts each; 4/lane)
        for (int sl = wave; sl < 32; sl += 8) {
          float a0x=1e30f, a1x=-1e30f, a0y=1e30f, a1y=-1e30f, a0z=1e30f, a1z=-1e30f;
          #pragma unroll
          for (int t = 0; t < 4; ++t) {
            float4 c = csorted[b2*NN + sl*256 + lane*4 + t];
            a0x = fminf(a0x, c.x); a1x = fmaxf(a1x, c.x);
            a0y = fminf(a0y, c.y); a1y = fmaxf(a1y, c.y);
            a0z = fminf(a0z, c.z); a1z = fmaxf(a1z, c.z);
          }
          a0x = wred_min(a0x); a1x = wred_max(a1x);
          a0y = wred_min(a0y); a1y = wred_max(a1y);
          a0z = wred_min(a0z); a1z = wred_max(a1z);
          if (lane == 63) {
            float* o = caabb + (b2*32 + sl)*8;
            o[0]=a0x; o[1]=a1x; o[2]=a0y; o[3]=a1y; o[4]=a0z; o[5]=a1z;
          }
        }
      }
      return;
    }
    // ---------- spinner role: wave 0 only; FMA activity; exit on fps done ----------
    if (tid >= 64) return;
    const int s0 = atomicAdd(spin_flag, 0);
    float a0 = 1.0f + tid, a1 = 2.0f, a2 = 3.0f, a3 = 4.0f;
    for (int outer = 0; outer < 50000; ++outer) {
      #pragma unroll
      for (int u = 0; u < 256; ++u) {
        a0 = fmaf(a0, 1.0000001f, 1e-7f);
        a1 = fmaf(a1, 0.9999999f, 2e-7f);
        a2 = fmaf(a2, 1.0000002f, 3e-7f);
        a3 = fmaf(a3, 0.9999998f, 4e-7f);
      }
      if (atomicAdd(spin_flag, 0) - s0 >= BB) break;
    }
    asm volatile("" :: "v"(a0), "v"(a1), "v"(a2), "v"(a3));
    return;
  }

  // ---------------- fps role: EXACT R13/R18 structure ----------------
  const int b = blk;
  const float* xb = xyz + b*3*NN;

  float tx[FPT], ty[FPT], tz[FPT];
  #pragma unroll
  for (int j = 0; j < FPT; ++j) {
    int i = tid + j*FTH;
    tx[j] = xb[i]; ty[j] = xb[NN+i]; tz[j] = xb[2*NN+i];
  }
  float mnx = tx[0], mxx = tx[0], mny = ty[0], mxy = ty[0], mnz = tz[0], mxz = tz[0];
  #pragma unroll
  for (int j = 1; j < FPT; ++j) {
    mnx = fminf(mnx, tx[j]); mxx = fmaxf(mxx, tx[j]);
    mny = fminf(mny, ty[j]); mxy = fmaxf(mxy, ty[j]);
    mnz = fminf(mnz, tz[j]); mxz = fmaxf(mxz, tz[j]);
  }
  mnx = wred_min(mnx); mxx = wred_max(mxx);
  mny = wred_min(mny); mxy = wred_max(mxy);
  mnz = wred_min(mnz); mxz = wred_max(mxz);
  if (lane == 63) {
    sred[wave*6+0] = mnx; sred[wave*6+1] = mxx; sred[wave*6+2] = mny;
    sred[wave*6+3] = mxy; sred[wave*6+4] = mnz; sred[wave*6+5] = mxz;
  }
  smi[tid] = 0;                       // zero hist region [0,512)
  __syncthreads();
  #pragma unroll
  for (int w = 0; w < 8; ++w) {
    mnx = fminf(mnx, sred[w*6+0]); mxx = fmaxf(mxx, sred[w*6+1]);
    mny = fminf(mny, sred[w*6+2]); mxy = fmaxf(mxy, sred[w*6+3]);
    mnz = fminf(mnz, sred[w*6+4]); mxz = fmaxf(mxz, sred[w*6+5]);
  }
  const float scx = 8.0f / (mxx - mnx + 1e-12f);
  const float scy = 8.0f / (mxy - mny + 1e-12f);
  const float scz = 8.0f / (mxz - mnz + 1e-12f);
  int cells[FPT];
  #pragma unroll
  for (int j = 0; j < FPT; ++j) {
    cells[j] = morton8(tx[j], ty[j], tz[j], mnx, mny, mnz, scx, scy, scz);
    atomicAdd(&smi[cells[j]], 1);
  }
  __syncthreads();
  for (int d = 1; d < 512; d <<= 1) {
    int v = smi[tid];
    int a = (tid >= d) ? smi[tid - d] : 0;
    __syncthreads();
    smi[tid] = v + a;
    __syncthreads();
  }
  {
    int excl = (tid == 0) ? 0 : smi[tid - 1];
    smi[512 + tid] = excl;
  }
  __syncthreads();
  #pragma unroll
  for (int j = 0; j < FPT; ++j) {
    int pos = atomicAdd(&smi[512 + cells[j]], 1);
    sxyz[pos] = make_float4(tx[j], ty[j], tz[j], 0.0f);
  }
  __syncthreads();
  v2f px[FPT/2], py[FPT/2], pz[FPT/2], dist[FPT/2];
  float bx0, bx1, by0, by1, bz0, bz1;
  {
    float4 c0 = sxyz[tid*FPT];
    bx0 = bx1 = c0.x; by0 = by1 = c0.y; bz0 = bz1 = c0.z;
    #pragma unroll
    for (int e = 0; e < FPT; ++e) {
      float4 cc = sxyz[tid*FPT + e];
      ((float*)px)[e] = cc.x; ((float*)py)[e] = cc.y; ((float*)pz)[e] = cc.z;
      ((float*)dist)[e] = 1e10f;
      bx0 = fminf(bx0, cc.x); bx1 = fmaxf(bx1, cc.x);
      by0 = fminf(by0, cc.y); by1 = fmaxf(by1, cc.y);
      bz0 = fminf(bz0, cc.z); bz1 = fmaxf(bz1, cc.z);
    }
  }
  float dmax = 1e10f;
  int   beste = 0;
  float cx = xb[0], cy = xb[NN], cz = xb[2*NN];   // iteration-0 centroid = ORIGINAL point 0
  __syncthreads();
  for (int it = 1; it < SS; ++it) {
    const int buf = it & 1;
    float gx = fmaxf(fmaxf(bx0 - cx, cx - bx1), 0.0f);
    float gy = fmaxf(fmaxf(by0 - cy, cy - by1), 0.0f);
    float gz = fmaxf(fmaxf(bz0 - cz, cz - bz1), 0.0f);
    float lb = gx*gx + gy*gy; lb = lb + gz*gz;
    if (lb * 0.99999f < dmax) {
      v2f cx2 = {cx, cx}, cy2 = {cy, cy}, cz2 = {cz, cz};
      v2f vmax = {-1.0f, -1.0f};
      #pragma unroll
      for (int j = 0; j < FPT/2; ++j) {
        v2f dx = px[j] - cx2, dy = py[j] - cy2, dz = pz[j] - cz2;
        v2f d = dx*dx + dy*dy;
        d = d + dz*dz;
        v2f nd = __builtin_elementwise_min(dist[j], d);
        dist[j] = nd;
        vmax = __builtin_elementwise_max(vmax, nd);
      }
      float mloc = fmaxf(vmax.x, vmax.y);
      int ce[FPT/2];
      #pragma unroll
      for (int j = 0; j < FPT/2; ++j) {
        int c = 0x7FFFFFFF;
        if (dist[j].y == mloc) c = 2*j + 1;
        if (dist[j].x == mloc) c = 2*j;
        ce[j] = c;
      }
      #pragma unroll
      for (int st = FPT/4; st >= 1; st >>= 1) {
        #pragma unroll
        for (int j = 0; j < st; ++j) ce[j] = ce[j] < ce[j+st] ? ce[j] : ce[j+st];
      }
      dmax = mloc;
      beste = ce[0];
    }
    // R18 wave argmax: f32 max ladder + ballot + readlane (verified)
    float wm = dmax;
    wm = wred_max(wm);
    wm = __int_as_float(__builtin_amdgcn_readlane(__float_as_int(wm), 63));
    unsigned long long em = __ballot(dmax == wm);
    int lw = (int)__ffsll((unsigned long long)em) - 1;
    int bi_w = __builtin_amdgcn_readlane((tid << 4) + beste, lw);
    if (lane == 63) skey[buf][wave] = ((unsigned long long)__float_as_uint(wm) << 32) | (unsigned)~bi_w;
    __syncthreads();
    const ulonglong2* kp = (const ulonglong2*)&skey[buf][0];
    ulonglong2 k01 = kp[0], k23 = kp[1], k45 = kp[2], k67 = kp[3];
    unsigned long long m0 = k01.x > k01.y ? k01.x : k01.y;
    unsigned long long m1 = k23.x > k23.y ? k23.x : k23.y;
    unsigned long long m2 = k45.x > k45.y ? k45.x : k45.y;
    unsigned long long m3 = k67.x > k67.y ? k67.x : k67.y;
    unsigned long long ma = m0 > m1 ? m0 : m1;
    unsigned long long mb = m2 > m3 ? m2 : m3;
    unsigned long long mk = ma > mb ? ma : mb;
    int mi = (int)(~(unsigned)mk);
    float4 c = sxyz[mi];
    if (tid == 0) smi[it] = mi;
    cx = c.x; cy = c.y; cz = c.z;
  }
  __syncthreads();
  // epilogue: write sampled coords; it=0 from ORIGINAL point 0
  for (int it = tid; it < SS; it += FTH) {
    float x, y, z;
    if (it == 0) { x = xb[0]; y = xb[NN]; z = xb[2*NN]; }
    else { float4 c = sxyz[smi[it]]; x = c.x; y = c.y; z = c.z; }
    out_newxyz[(b*3+0)*SS + it] = x;
    out_newxyz[(b*3+1)*SS + it] = y;
    out_newxyz[(b*3+2)*SS + it] = z;
  }
  // ---- Morton-sort the 2048 samples -> qsorted (+orig s), 8 slice AABBs -> qaabb (verified R19) ----
  float4 qp4[4]; int qj4[4], qc4[4];
  #pragma unroll
  for (int k2 = 0; k2 < 4; ++k2) {
    int j = tid + k2*FTH;
    float4 p;
    if (j == 0) p = make_float4(xb[0], xb[NN], xb[2*NN], 0.0f);
    else        p = sxyz[smi[j]];
    qp4[k2] = p; qj4[k2] = j;
  }
  __syncthreads();            // done reading smi history
  smi[tid] = 0;
  __syncthreads();
  #pragma unroll
  for (int k2 = 0; k2 < 4; ++k2) {
    qc4[k2] = morton8(qp4[k2].x, qp4[k2].y, qp4[k2].z, mnx, mny, mnz, scx, scy, scz);
    atomicAdd(&smi[qc4[k2]], 1);
  }
  __syncthreads();
  for (int d = 1; d < 512; d <<= 1) {
    int v = smi[tid];
    int a = (tid >= d) ? smi[tid - d] : 0;
    __syncthreads();
    smi[tid] = v + a;
    __syncthreads();
  }
  { int excl = (tid == 0) ? 0 : smi[tid - 1]; smi[512 + tid] = excl; }
  __syncthreads();
  #pragma unroll
  for (int k2 = 0; k2 < 4; ++k2) {
    int pos = atomicAdd(&smi[512 + qc4[k2]], 1);
    qsorted[b*SS + pos] = make_float4(qp4[k2].x, qp4[k2].y, qp4[k2].z, __int_as_float(qj4[k2]));
  }
  __syncthreads();            // drain scatter; same-CU reads below coherent
  {
    float a0x=1e30f, a1x=-1e30f, a0y=1e30f, a1y=-1e30f, a0z=1e30f, a1z=-1e30f;
    #pragma unroll
    for (int t = 0; t < 4; ++t) {
      float4 c = qsorted[b*SS + wave*256 + lane*4 + t];
      a0x = fminf(a0x, c.x); a1x = fmaxf(a1x, c.x);
      a0y = fminf(a0y, c.y); a1y = fmaxf(a1y, c.y);
      a0z = fminf(a0z, c.z); a1z = fmaxf(a1z, c.z);
    }
    a0x = wred_min(a0x); a1x = wred_max(a1x);
    a0y = wred_min(a0y); a1y = wred_max(a1y);
    a0z = wred_min(a0z); a1z = wred_max(a1z);
    if (lane == 63) {
      float* o = qaabb + (b*8 + wave)*8;
      o[0]=a0x; o[1]=a1x; o[2]=a0y; o[3]=a1y; o[4]=a0z; o[5]=a1z;
    }
  }
  if (tid == 0) atomicAdd(spin_flag, 1);   // release spinners
}

// ---------------- KNN: block = 64 sorted queries, 8 waves split slices (zigzag rank), per-wave theta skip ----------------
#define KTH 512
__global__ __launch_bounds__(KTH) void knn_kernel(
    const float4* __restrict__ qsorted, // [B][2048]
    const float*  __restrict__ qaabb,   // [B][8][8]
    const float4* __restrict__ csorted, // [B][8192]
    const float*  __restrict__ caabb,   // [B][32][8]
    int* __restrict__ out1,             // [B,S,K] vs xyz (orig indices)
    int* __restrict__ out2)             // [B,S,K] self (s indices)
{
  #pragma clang fp contract(off)
  __shared__ float4 sc[8][256];          // per-wave slice staging (32 KB)
  __shared__ int    sidx[8][256];        // 8 KB
  __shared__ float  smd[8*64*17];        // per-wave top-16 dists (pad 17) ~34.8 KB
  __shared__ int    smj[8*64*17];        // per-wave top-16 idxs
  const int bid = blockIdx.x;
  const int half = bid >> 7;             // 0: vs xyz, 1: self
  const int rem = bid & 127;
  const int b = rem >> 5;
  const int wslot = rem & 31;            // sorted-query group
  const int wave = threadIdx.x >> 6, lane = threadIdx.x & 63;
  const float4* cand = half ? (qsorted + b*SS) : (csorted + b*NN);
  const float*  aabb = half ? (qaabb + b*8*8) : (caabb + b*32*8);
  const int nsl = half ? 8 : 32;
  const int sh = half ? (wslot >> 2) : wslot;   // home slice
  const int nj = nsl >> 3;               // slices per wave: 4 (NN) / 1 (self)
  int* outidx = half ? out2 : out1;

  // all 8 waves load the SAME 64 sorted queries
  float4 q = qsorted[b*SS + wslot*64 + lane];
  const int orig_s = __float_as_int(q.w);
  const float qx = q.x, qy = q.y, qz = q.z;
  float sq = qx*qx + qy*qy; sq = sq + qz*qz;
  float d16[16]; int i16[16];
  #pragma unroll
  for (int j = 0; j < 16; ++j) { d16[j] = 1e30f; i16[j] = 0x7FFFFFFF; }

  for (int jj = 0; jj < nj; ++jj) {
    const int j = wave + jj*8;           // zigzag rank: wave's first slice is its nearest
    const int off = (j + 1) >> 1;
    const int s = (sh + ((j & 1) ? off : -off)) & (nsl - 1);   // distinct mod nsl over j=0..nsl-1
    const float* ab = aabb + s*8;
    // per-lane exact skip vs this wave's own theta (verified R19 margin: false-skip impossible;
    // theta only shrinks -> skip valid at check time is final-valid for the wave's list)
    float gx = fmaxf(fmaxf(ab[0] - qx, qx - ab[1]), 0.0f);
    float gy = fmaxf(fmaxf(ab[2] - qy, qy - ab[3]), 0.0f);
    float gz = fmaxf(fmaxf(ab[4] - qz, qz - ab[5]), 0.0f);
    float lbnd = gx*gx + gy*gy; lbnd = lbnd + gz*gz;
    bool skip = (lbnd * 0.9999f - 1e-3f) > d16[15];
    if (__all(skip)) continue;
    // stage slice s into this wave's private LDS region (wave-synchronous; no barrier needed)
    #pragma unroll
    for (int t = 0; t < 4; ++t) {
      float4 c = cand[s*256 + t*64 + lane];
      float pp = c.x*c.x + c.y*c.y; pp = pp + c.z*c.z;
      sidx[wave][t*64 + lane] = __float_as_int(c.w);
      sc[wave][t*64 + lane] = make_float4(c.x, c.y, c.z, pp);
    }
    for (int t = 0; t < 256; ++t) {
      float4 c = sc[wave][t];
      float qp = qx*c.x + qy*c.y; qp = qp + qz*c.z;
      float d2 = (sq + c.w) - 2.0f*qp;
      if (d2 < d16[15]) {
        d16[15] = d2; i16[15] = sidx[wave][t];
        #pragma unroll
        for (int u = 15; u > 0; --u) {
          if (d16[u] < d16[u-1]) {
            float td = d16[u]; d16[u] = d16[u-1]; d16[u-1] = td;
            int   ti = i16[u]; i16[u] = i16[u-1]; i16[u-1] = ti;
          }
        }
      }
    }
  }
  const int offm = (wave*64 + lane)*17;
  #pragma unroll
  for (int j = 0; j < 16; ++j) { smd[offm+j] = d16[j]; smj[offm+j] = i16[j]; }
  __syncthreads();
  if (wave == 0) {
    // 8-way stable merge: tie-break on smaller index = stable lax.top_k semantics (verbatim R8)
    int p[8] = {0,0,0,0,0,0,0,0};
    for (int o = 0; o < 16; ++o) {
      float bd = 3e38f; int bi = 0x7FFFFFFF, bw = 0;
      #pragma unroll
      for (int w = 0; w < 8; ++w) {
        float d = smd[(w*64+lane)*17 + p[w]];
        int   i = smj[(w*64+lane)*17 + p[w]];
        if (d < bd || (d == bd && i < bi)) { bd = d; bi = i; bw = w; }
      }
      p[bw]++;
      outidx[(b*SS + orig_s)*KK + o] = bi;
    }
  }
}

// ---------------- Transition-down conv + stats + max over K (td_wT: coalesced weight reads) ----------------
__global__ __launch_bounds__(128) void td_kernel(
    const float* __restrict__ ptst,    // [B,N,64] point-major
    const float* __restrict__ xyz,     // [B,3,N]
    const float* __restrict__ newxyz,  // [B,3,S]
    const int* __restrict__ gidx,      // [B,S,K]
    const float* __restrict__ td_wT,   // [67][128] transposed
    const float* __restrict__ td_b,    // [128]
    float* __restrict__ ymax,          // [B*S,128]
    float* __restrict__ psum,          // [B*S,128]
    float* __restrict__ psq)
{
  const int bs = blockIdx.x;
  const int b = bs >> 11, s = bs & (SS-1);
  const int t = threadIdx.x;
  __shared__ int gi[KK];
  __shared__ float g[67*17];           // stride 17: conflict-free writes
  if (t < KK) gi[t] = gidx[bs*KK + t];
  __syncthreads();
  #pragma unroll
  for (int base = 0; base < 1024; base += 128) {
    int idx = base + t;
    int i = idx & 63, k = idx >> 6;
    g[i*17 + k] = ptst[(b*NN + gi[k])*64 + i];
  }
  if (t < 48) {
    int c = t >> 4, k = t & 15;
    g[(64+c)*17 + k] = xyz[(b*3+c)*NN + gi[k]] - newxyz[(b*3+c)*SS + s];
  }
  __syncthreads();
  float acc[KK];
  #pragma unroll
  for (int k = 0; k < KK; ++k) acc[k] = 0.0f;
  for (int i = 0; i < 67; ++i) {
    float w = td_wT[i*128 + t];        // coalesced (same value/order as td_w[t*67+i])
    #pragma unroll
    for (int k = 0; k < KK; ++k) acc[k] = fmaf(w, g[i*17 + k], acc[k]);
  }
  float bias = td_b[t];
  float mx = -1e30f, s1 = 0.f, s2 = 0.f;
  #pragma unroll
  for (int k = 0; k < KK; ++k) {
    float y = acc[k] + bias;
    mx = fmaxf(mx, y);
    s1 += y;
    s2 = fmaf(y, y, s2);
  }
  ymax[bs*128 + t] = mx;             // coalesced
  psum[bs*128 + t] = s1;             // coalesced
  psq [bs*128 + t] = s2;             // coalesced
}

// ---------------- bn_partial + fused bn_final (last-block trick; counter zeroed by fps launch) ----------------
__global__ __launch_bounds__(256) void bn_partial(
    const float* __restrict__ psum, const float* __restrict__ psq,
    float* __restrict__ part1, float* __restrict__ part2,
    const float* __restrict__ gamma, const float* __restrict__ beta,
    float* __restrict__ scale, float* __restrict__ bias,
    int* __restrict__ counter)
{
  const int blk = blockIdx.x, t = threadIdx.x;
  const int c = t & 127, half = t >> 7;
  const float* ps = psum + (blk*64 + half*32)*128;
  const float* pq = psq  + (blk*64 + half*32)*128;
  float s1 = 0.f, s2 = 0.f;
  for (int r = 0; r < 32; ++r) { s1 += ps[r*128 + c]; s2 += pq[r*128 + c]; }
  __shared__ float sh1[256], sh2[256];
  __shared__ int s_last;
  sh1[t] = s1; sh2[t] = s2;
  __syncthreads();
  if (t < 128) {
    part1[blk*128 + t] = sh1[t] + sh1[t+128];
    part2[blk*128 + t] = sh2[t] + sh2[t+128];
  }
  __syncthreads();
  __threadfence();
  if (t == 0) s_last = (atomicAdd(counter, 1) == 127) ? 1 : 0;
  __syncthreads();
  if (!s_last) return;
  __threadfence();
  float f1 = 0.f, f2 = 0.f;
  for (int j = half*64; j < half*64 + 64; ++j) {
    f1 += part1[j*128 + c];
    f2 += part2[j*128 + c];
  }
  sh1[t] = f1; sh2[t] = f2;
  __syncthreads();
  if (t < 128) {
    float a1 = sh1[t] + sh1[t+128];
    float a2 = sh2[t] + sh2[t+128];
    const float n = (float)(BB*SS*KK);
    float mean = a1/n;
    float var  = a2/n - mean*mean;
    float sc = gamma[t] / sqrtf(var + 1e-5f);
    scale[t] = sc;
    bias[t]  = beta[t] - mean*sc;
  }
}

// ---------------- r1_first: fused td_final + r1 (i=0); transposed weights ----------------
__global__ __launch_bounds__(128) void r1_first(
    const float* __restrict__ ymax,   // [B*S,128]
    const float* __restrict__ scale, const float* __restrict__ bias,
    const float* __restrict__ bwT, const float* __restrict__ bb,   // [128*32] (c*32+r), [32]
    const float* __restrict__ qwT,                                 // [32*96] (c*96+r)
    float* __restrict__ pts,          // [B*S,128] (written here)
    float* __restrict__ qkv)
{
  const int bs = blockIdx.x;
  const int t = threadIdx.x;
  __shared__ float pcol[128];
  __shared__ float p[32];
  float v = fmaxf(fmaf(ymax[bs*128 + t], scale[t], bias[t]), 0.0f);
  pts[bs*128 + t] = v;
  pcol[t] = v;
  __syncthreads();
  if (t < 32) {
    float acc = 0.f;
    for (int j = 0; j < 128; ++j) acc = fmaf(bwT[j*32 + t], pcol[j], acc);  // coalesced
    p[t] = acc + bb[t];
  }
  __syncthreads();
  if (t < 96) {
    float acc = 0.f;
    #pragma unroll
    for (int j = 0; j < 32; ++j) acc = fmaf(qwT[j*96 + t], p[j], acc);      // coalesced
    qkv[bs*96 + t] = acc;
  }
}

// ---------------- Res block part 1; transposed weights ----------------
__global__ __launch_bounds__(128) void r1_kernel(
    const float* __restrict__ pts,
    const float* __restrict__ bwT, const float* __restrict__ bb,   // [128*32],[32]
    const float* __restrict__ qwT,                                 // [32*96]
    float* __restrict__ qkv)
{
  const int bs = blockIdx.x;
  const int t = threadIdx.x;
  __shared__ float pcol[128];
  __shared__ float p[32];
  pcol[t] = pts[bs*128 + t];
  __syncthreads();
  if (t < 32) {
    float acc = 0.f;
    for (int j = 0; j < 128; ++j) acc = fmaf(bwT[j*32 + t], pcol[j], acc);  // coalesced
    p[t] = acc + bb[t];
  }
  __syncthreads();
  if (t < 96) {
    float acc = 0.f;
    #pragma unroll
    for (int j = 0; j < 32; ++j) acc = fmaf(qwT[j*96 + t], p[j], acc);      // coalesced
    qkv[bs*96 + t] = acc;
  }
}

// ---------------- Res block part 2; aw1T/fwT transposed; outT!=null => transposed final store ----------------
__global__ __launch_bounds__(128) void r2_kernel(
    const float* __restrict__ qkv,
    const float* __restrict__ newxyz, // [B,3,S]
    const int* __restrict__ sgidx,    // [B,S,K]
    const float* __restrict__ pw1, const float* __restrict__ pb1,  // [64,3],[64]
    const float* __restrict__ pw2, const float* __restrict__ pb2,  // [32,64],[32]
    const float* __restrict__ aw1T, const float* __restrict__ ab1, // [32*128] (c*128+r),[128]
    const float* __restrict__ aw2, const float* __restrict__ ab2,  // [32,128],[32]
    const float* __restrict__ fwT,  const float* __restrict__ fb,  // [32*128],[128]
    float* __restrict__ pts,          // [B*S,128]  (+= when outT==null)
    float* __restrict__ outT)         // [B,128,S] or null
{
  const int bs = blockIdx.x;
  const int b = bs >> 11, s = bs & (SS-1);
  const int t = threadIdx.x;
  __shared__ int sgi[KK];
  __shared__ float qv[32];
  __shared__ float kn[32*17], vn[32*17];   // stride 17: conflict-free
  __shared__ float gx[3*KK];
  __shared__ float h1[64*KK];
  __shared__ float x2[32*KK];
  __shared__ float a1[128*17];             // stride 17
  __shared__ float simb[32*KK];
  __shared__ float agg[32];
  if (t < KK) sgi[t] = sgidx[bs*KK + t];
  __syncthreads();
  if (t < 32) qv[t] = qkv[bs*96 + t];
  for (int idx = t; idx < 32*KK; idx += 128) {
    int k = idx >> 5, c = idx & 31;
    int base = (b*SS + sgi[k])*96;
    kn[c*17+k] = qkv[base + 32 + c];
    vn[c*17+k] = qkv[base + 64 + c];
  }
  if (t < 3*KK) {
    int c = t >> 4, k = t & 15;
    gx[t] = newxyz[(b*3+c)*SS + s] - newxyz[(b*3+c)*SS + sgi[k]];
  }
  __syncthreads();
  for (int idx = t; idx < 64*KK; idx += 128) {
    int c = idx >> 4, k = idx & 15;
    float acc = 0.f;
    #pragma unroll
    for (int j = 0; j < 3; ++j) acc = fmaf(pw1[c*3+j], gx[j*KK+k], acc);
    h1[idx] = fmaxf(acc + pb1[c], 0.0f);
  }
  __syncthreads();
  for (int idx = t; idx < 32*KK; idx += 128) {
    int c = idx >> 4, k = idx & 15;
    float acc = 0.f;
    const float* w = pw2 + c*64;
    for (int j = 0; j < 64; ++j) acc = fmaf(w[j], h1[j*KK+k], acc);
    float r = acc + pb2[c];
    x2[idx] = (qv[c] - kn[c*17+k]) + r;   // qk_rel + rel
    vn[c*17+k] = vn[c*17+k] + r;          // v + rel
  }
  __syncthreads();
  {
    float acc[KK];
    #pragma unroll
    for (int k = 0; k < KK; ++k) acc[k] = 0.f;
    for (int j = 0; j < 32; ++j) {
      float wv = aw1T[j*128 + t];        // coalesced (same value/order as aw1[t*32+j])
      #pragma unroll
      for (int k = 0; k < KK; ++k) acc[k] = fmaf(wv, x2[j*KK+k], acc[k]);
    }
    float bv = ab1[t];
    #pragma unroll
    for (int k = 0; k < KK; ++k) a1[t*17+k] = fmaxf(acc[k] + bv, 0.0f);
  }
  __syncthreads();
  for (int idx = t; idx < 32*KK; idx += 128) {
    int c = idx >> 4, k = idx & 15;
    float acc = 0.f;
    const float* w = aw2 + c*128;
    for (int j = 0; j < 128; ++j) acc = fmaf(w[j], a1[j*17+k], acc);
    simb[idx] = acc + ab2[c];
  }
  __syncthreads();
  if (t < 32) {
    float m = -1e30f;
    #pragma unroll
    for (int k = 0; k < KK; ++k) m = fmaxf(m, simb[t*KK+k]);
    float sum = 0.f;
    float e[KK];
    #pragma unroll
    for (int k = 0; k < KK; ++k) { e[k] = __expf(simb[t*KK+k] - m); sum += e[k]; }
    float inv = 1.0f / sum;
    float a = 0.f;
    #pragma unroll
    for (int k = 0; k < KK; ++k) a = fmaf(e[k]*inv, vn[t*17+k], a);
    agg[t] = a;
  }
  __syncthreads();
  {
    float acc = 0.f;
    #pragma unroll
    for (int j = 0; j < 32; ++j) acc = fmaf(fwT[j*128 + t], agg[j], acc);   // coalesced
    float val = pts[bs*128 + t] + (acc + fb[t]);
    if (outT) outT[(b*128 + t)*SS + s] = val;
    else      pts[bs*128 + t] = val;
  }
}

extern "C" void kernel_launch(void* const* d_in, const int* in_sizes, int n_in,
                              void* d_out, int out_size, void* d_ws, size_t ws_size,
                              hipStream_t stream) {
  const float* xyz      = (const float*)d_in[0];
  const float* points   = (const float*)d_in[1];
  const float* td_w     = (const float*)d_in[2];
  const float* td_b     = (const float*)d_in[3];
  const float* td_gamma = (const float*)d_in[4];
  const float* td_beta  = (const float*)d_in[5];
  const float* bw  = (const float*)d_in[6];
  const float* bb  = (const float*)d_in[7];
  const float* qw  = (const float*)d_in[8];
  const float* pw1 = (const float*)d_in[9];
  const float* pb1 = (const float*)d_in[10];
  const float* pw2 = (const float*)d_in[11];
  const float* pb2 = (const float*)d_in[12];
  const float* aw1 = (const float*)d_in[13];
  const float* ab1 = (const float*)d_in[14];
  const float* aw2 = (const float*)d_in[15];
  const float* ab2 = (const float*)d_in[16];
  const float* fw  = (const float*)d_in[17];
  const float* fb  = (const float*)d_in[18];
  float* out = (float*)d_out;
  float* out_newxyz = out;                 // [B,3,S]
  float* out_pts    = out + BB*3*SS;       // [B,128,S]

  char* w = (char*)d_ws;
  int*   gidx   = (int*)w;   w += BB*SS*KK*sizeof(int);
  int*   sgidx  = (int*)w;   w += BB*SS*KK*sizeof(int);
  float* ymax   = (float*)w; w += BB*128*SS*sizeof(float);
  float* psum   = (float*)w; w += 128*BB*SS*sizeof(float);
  float* psq    = (float*)w; w += 128*BB*SS*sizeof(float);
  float* part1  = (float*)w; w += 128*128*sizeof(float);
  float* part2  = (float*)w; w += 128*128*sizeof(float);
  float* bnscale= (float*)w; w += 256*sizeof(float);
  float* bnbias = (float*)w; w += 256*sizeof(float);
  float* pts    = (float*)w; w += BB*128*SS*sizeof(float);
  float* qkv    = (float*)w; w += BB*96*SS*sizeof(float);
  float* ptst   = (float*)w; w += BB*NN*64*sizeof(float);   // [B,N,64]
  int*   flags  = (int*)w;   w += 256;   // [0]=spinner release, [8]=bn counter
  float4* csorted = (float4*)w; w += BB*NN*sizeof(float4);  // 512 KB
  float*  caabb   = (float*)w;  w += BB*32*8*sizeof(float);
  float4* qsorted = (float4*)w; w += BB*SS*sizeof(float4);  // 128 KB
  float*  qaabb   = (float*)w;  w += BB*8*8*sizeof(float);
  float* td_wT  = (float*)w; w += 67*128*sizeof(float);
  float* bwT    = (float*)w; w += 2*4096*sizeof(float);
  float* qwT    = (float*)w; w += 2*3072*sizeof(float);
  float* aw1T   = (float*)w; w += 2*4096*sizeof(float);
  float* fwT    = (float*)w; w += 2*4096*sizeof(float);

  fps_kernel<<<BB + TRB + SPB, FTH, 0, stream>>>(xyz, points, td_w, bw, qw, aw1, fw,
      out_newxyz, ptst, csorted, caabb, qsorted, qaabb,
      td_wT, bwT, qwT, aw1T, fwT, flags);
  knn_kernel<<<256, KTH, 0, stream>>>(qsorted, qaabb, csorted, caabb, gidx, sgidx);
  td_kernel<<<BB*SS, 128, 0, stream>>>(ptst, xyz, out_newxyz, gidx, td_wT, td_b, ymax, psum, psq);
  bn_partial<<<128, 256, 0, stream>>>(psum, psq, part1, part2,
      td_gamma, td_beta, bnscale, bnbias, &flags[8]);
  r1_first<<<BB*SS, 128, 0, stream>>>(ymax, bnscale, bnbias, bwT, bb, qwT, pts, qkv);
  r2_kernel<<<BB*SS, 128, 0, stream>>>(qkv, out_newxyz, sgidx,
      pw1, pb1, pw2, pb2, aw1T, ab1, aw2, ab2, fwT, fb, pts, nullptr);
  r1_kernel<<<BB*SS, 128, 0, stream>>>(pts, bwT + 4096, bb + 32, qwT + 3072, qkv);
  r2_kernel<<<BB*SS, 128, 0, stream>>>(qkv, out_newxyz, sgidx,
      pw1 + 64*3, pb1 + 64, pw2 + 32*64, pb2 + 32,
      aw1T + 4096, ab1 + 128, aw2 + 32*128, ab2 + 32,
      fwT + 4096, fb + 128, pts, out_pts);
}